// Round 5
// baseline (2145.827 us; speedup 1.0000x reference)
//
#include <hip/hip_runtime.h>

#define EPSBN 1e-5f
#define NB 1024           // buckets (dst >> 8), 256 nodes per bucket
#define GB 1024           // blocks for cnt/reorder tiles

typedef float vf4 __attribute__((ext_vector_type(4)));
typedef unsigned int uint32;

__device__ __forceinline__ float ftanh(float x) {
    return 1.0f - 2.0f / (__expf(2.0f * x) + 1.0f);
}

__device__ __forceinline__ float wave_sum(float v) {
#pragma unroll
    for (int off = 32; off > 0; off >>= 1) v += __shfl_down(v, off);
    return v;
}

__device__ __forceinline__ void z1_of(const float4 hi, const float4 hj,
                                      const float* __restrict__ w, const float* __restrict__ b,
                                      float* z) {
#pragma unroll
    for (int j = 0; j < 8; ++j) {
        z[j] = b[j]
             + hi.x * w[0 * 8 + j] + hi.y * w[1 * 8 + j] + hi.z * w[2 * 8 + j] + hi.w * w[3 * 8 + j]
             + hj.x * w[4 * 8 + j] + hj.y * w[5 * 8 + j] + hj.z * w[6 * 8 + j] + hj.w * w[7 * 8 + j];
    }
}

__device__ __forceinline__ void mat8x8(const float* u, const float* __restrict__ w,
                                       const float* __restrict__ b, float* z) {
#pragma unroll
    for (int j = 0; j < 8; ++j) {
        float t = b[j];
#pragma unroll
        for (int k = 0; k < 8; ++k) t += u[k] * w[k * 8 + j];
        z[j] = t;
    }
}

__device__ __forceinline__ void mat8x4(const float* u, const float* __restrict__ w,
                                       const float* __restrict__ b, float* z) {
#pragma unroll
    for (int c = 0; c < 4; ++c) {
        float t = b[c];
#pragma unroll
        for (int k = 0; k < 8; ++k) t += u[k] * w[k * 4 + c];
        z[c] = t;
    }
}

template <int NV>
__device__ __forceinline__ void block_reduce_atomics(float* a, float* __restrict__ sums) {
    __shared__ float red[NV * 4];
    int wid = threadIdx.x >> 6, lane = threadIdx.x & 63;
#pragma unroll
    for (int i = 0; i < NV; ++i) {
        float v = wave_sum(a[i]);
        if (lane == 0) red[i * 4 + wid] = v;
    }
    __syncthreads();
    if (threadIdx.x < NV) {
        float v = red[threadIdx.x * 4 + 0] + red[threadIdx.x * 4 + 1]
                + red[threadIdx.x * 4 + 2] + red[threadIdx.x * 4 + 3];
        atomicAdd(&sums[threadIdx.x], v);
    }
}

// ---------------- node input projection ----------------
__global__ __launch_bounds__(256) void k_h(const float* __restrict__ pos, const float* __restrict__ vel,
                                           const float* __restrict__ w, const float* __restrict__ b,
                                           float4* __restrict__ h, int n) {
    int i = blockIdx.x * blockDim.x + threadIdx.x;
    if (i >= n) return;
    float2 p = ((const float2*)pos)[i];
    float2 v = ((const float2*)vel)[i];
    float o[4];
#pragma unroll
    for (int d = 0; d < 4; ++d)
        o[d] = b[d] + p.x * w[0 * 4 + d] + p.y * w[1 * 4 + d] + v.x * w[2 * 4 + d] + v.y * w[3 * 4 + d];
    h[i] = make_float4(o[0], o[1], o[2], o[3]);
}

// ---------------- count: per-(block,bucket) histogram, LDS atomics only ----------------
__global__ __launch_bounds__(256) void k_cnt(const int* __restrict__ dst, uint32* __restrict__ cntmat,
                                             int E_, int T) {
    __shared__ uint32 hist[NB];
    for (int b = threadIdx.x; b < NB; b += 256) hist[b] = 0;
    __syncthreads();
    int lo = blockIdx.x * T, hi2 = min(E_, lo + T);
    for (int e = lo + threadIdx.x; e < hi2; e += 256) {
        int d = __builtin_nontemporal_load(dst + e);
        atomicAdd(&hist[d >> 8], 1u);
    }
    __syncthreads();
    for (int b = threadIdx.x; b < NB; b += 256)
        cntmat[(size_t)b * GB + blockIdx.x] = hist[b];
}

// block-scan of 1024 uints (256 threads x 4), exclusive, shared device fn
__device__ __forceinline__ void scan1024(uint32* v /*4 per thread*/, uint32* excl_out, uint32* total) {
    __shared__ uint32 ts[256];
    uint32 local = v[0] + v[1] + v[2] + v[3];
    ts[threadIdx.x] = local;
    __syncthreads();
    for (int off = 1; off < 256; off <<= 1) {
        uint32 t = (threadIdx.x >= (uint32)off) ? ts[threadIdx.x - off] : 0u;
        __syncthreads();
        ts[threadIdx.x] += t;
        __syncthreads();
    }
    *excl_out = ts[threadIdx.x] - local;
    *total = ts[255];
}

// scan each bucket row of cntmat in-place (exclusive), write row totals
__global__ __launch_bounds__(256) void k_scanA(uint32* __restrict__ cntmat, uint32* __restrict__ rowtot) {
    size_t base = (size_t)blockIdx.x * GB + threadIdx.x * 4;
    uint32 v[4];
#pragma unroll
    for (int k = 0; k < 4; ++k) v[k] = cntmat[base + k];
    uint32 excl, tot;
    scan1024(v, &excl, &tot);
    uint32 run = excl;
#pragma unroll
    for (int k = 0; k < 4; ++k) { uint32 t = v[k]; cntmat[base + k] = run; run += t; }
    if (threadIdx.x == 0) rowtot[blockIdx.x] = tot;
}

// scan rowtot -> bucket base (exclusive); rowtot preserved
__global__ __launch_bounds__(256) void k_scanB(const uint32* __restrict__ rowtot, uint32* __restrict__ bbase) {
    uint32 v[4];
#pragma unroll
    for (int k = 0; k < 4; ++k) v[k] = rowtot[threadIdx.x * 4 + k];
    uint32 excl, tot;
    scan1024(v, &excl, &tot);
    uint32 run = excl;
#pragma unroll
    for (int k = 0; k < 4; ++k) { uint32 t = v[k]; bbase[threadIdx.x * 4 + k] = run; run += t; }
    if (threadIdx.x == 0) bbase[NB] = tot;
}

// ---------------- reorder + gather + z1 stats (LDS cursors, no global atomics) ----------------
__global__ __launch_bounds__(256) void k_reorder(const int* __restrict__ idx, const float4* __restrict__ h,
                                                 const float* __restrict__ w1, const float* __restrict__ b1,
                                                 const uint32* __restrict__ cntmat, const uint32* __restrict__ bbase,
                                                 vf4* __restrict__ rec, unsigned char* __restrict__ ids,
                                                 float* __restrict__ sums, int E_, int T) {
    __shared__ uint32 cur[NB];
    for (int b = threadIdx.x; b < NB; b += 256)
        cur[b] = bbase[b] + cntmat[(size_t)b * GB + blockIdx.x];
    float a[16];
#pragma unroll
    for (int i = 0; i < 16; ++i) a[i] = 0.f;
    __syncthreads();
    int lo = blockIdx.x * T, hi2 = min(E_, lo + T);
    for (int e = lo + threadIdx.x; e < hi2; e += 256) {
        int s = __builtin_nontemporal_load(idx + e);
        int d = __builtin_nontemporal_load(idx + E_ + e);
        float4 hi = h[d], hj = h[s];
        float z[8];
        z1_of(hi, hj, w1, b1, z);
#pragma unroll
        for (int j = 0; j < 8; ++j) { a[j] += z[j]; a[8 + j] += z[j] * z[j]; }
        uint32 pos = atomicAdd(&cur[d >> 8], 1u);
        vf4 vi = {hi.x, hi.y, hi.z, hi.w};
        vf4 vj = {hj.x, hj.y, hj.z, hj.w};
        rec[2 * (size_t)pos] = vi;          // regular stores: let L2 write-combine
        rec[2 * (size_t)pos + 1] = vj;
        ids[pos] = (unsigned char)(d & 255);
    }
    block_reduce_atomics<16>(a, sums);
}

// ---------------- finalize BN stats -> scale/shift ----------------
__global__ void k_fin(const float* __restrict__ sums, float* __restrict__ ss,
                      const float* __restrict__ g, const float* __restrict__ be,
                      int d, float inv_count) {
    int j = threadIdx.x;
    if (j >= d) return;
    float mu = sums[j] * inv_count;
    float var = sums[d + j] * inv_count - mu * mu;
    float s = g[j] * rsqrtf(var + EPSBN);
    ss[j] = s;
    ss[d + j] = be[j] - mu * s;
}

// ---------------- E2: sequential record read -> z2 stats ----------------
__global__ __launch_bounds__(256) void e_pass2(const vf4* __restrict__ rec,
                                               const float* __restrict__ w1, const float* __restrict__ b1,
                                               const float* __restrict__ ss1,
                                               const float* __restrict__ w2, const float* __restrict__ b2,
                                               float* __restrict__ sums2, int E_) {
    float a[8];
#pragma unroll
    for (int i = 0; i < 8; ++i) a[i] = 0.f;
    int stride = gridDim.x * blockDim.x;
    for (int e = blockIdx.x * blockDim.x + threadIdx.x; e < E_; e += stride) {
        vf4 vi = __builtin_nontemporal_load(&rec[2 * (size_t)e]);
        vf4 vj = __builtin_nontemporal_load(&rec[2 * (size_t)e + 1]);
        float4 hi = make_float4(vi.x, vi.y, vi.z, vi.w);
        float4 hj = make_float4(vj.x, vj.y, vj.z, vj.w);
        float z[8], m1[8], z2[4];
        z1_of(hi, hj, w1, b1, z);
#pragma unroll
        for (int j = 0; j < 8; ++j) m1[j] = ftanh(z[j] * ss1[j] + ss1[8 + j]);
        mat8x4(m1, w2, b2, z2);
#pragma unroll
        for (int c = 0; c < 4; ++c) { a[c] += z2[c]; a[4 + c] += z2[c] * z2[c]; }
    }
    block_reduce_atomics<8>(a, sums2);
}

// ---------------- aggregate: one block per bucket, LDS accumulators, no global atomics ----------------
__global__ __launch_bounds__(256) void e_aggr(const vf4* __restrict__ rec, const unsigned char* __restrict__ ids,
                                              const uint32* __restrict__ bbase, const uint32* __restrict__ rowtot,
                                              const float* __restrict__ w1, const float* __restrict__ b1,
                                              const float* __restrict__ ss1,
                                              const float* __restrict__ w2, const float* __restrict__ b2,
                                              const float* __restrict__ ss2,
                                              float* __restrict__ acc, int n) {
    __shared__ float lacc[256 * 5];
    for (int k = threadIdx.x; k < 256 * 5; k += 256) lacc[k] = 0.f;
    __syncthreads();
    uint32 start = bbase[blockIdx.x];
    uint32 end = start + rowtot[blockIdx.x];
    for (uint32 e = start + threadIdx.x; e < end; e += 256) {
        vf4 vi = __builtin_nontemporal_load(&rec[2 * (size_t)e]);
        vf4 vj = __builtin_nontemporal_load(&rec[2 * (size_t)e + 1]);
        int id = __builtin_nontemporal_load(ids + e);
        bool zero = (vi.x == vj.x) && (vi.y == vj.y) && (vi.z == vj.z) && (vi.w == vj.w);
        if (!zero) {
            float4 hi = make_float4(vi.x, vi.y, vi.z, vi.w);
            float4 hj = make_float4(vj.x, vj.y, vj.z, vj.w);
            float z[8], m1[8], z2[4], m2[4];
            z1_of(hi, hj, w1, b1, z);
#pragma unroll
            for (int j = 0; j < 8; ++j) m1[j] = ftanh(z[j] * ss1[j] + ss1[8 + j]);
            mat8x4(m1, w2, b2, z2);
#pragma unroll
            for (int c = 0; c < 4; ++c) m2[c] = ftanh(z2[c] * ss2[c] + ss2[4 + c]);
#pragma unroll
            for (int c = 0; c < 4; ++c) atomicAdd(&lacc[id * 5 + c], m2[c]);
        }
        atomicAdd(&lacc[id * 5 + 4], 1.0f);
    }
    __syncthreads();
    int node = (blockIdx.x << 8) + threadIdx.x;
    if (node < n) {
        float* ap = acc + 8 * (size_t)node;
        ap[0] = lacc[threadIdx.x * 5 + 0];
        ap[1] = lacc[threadIdx.x * 5 + 1];
        ap[2] = lacc[threadIdx.x * 5 + 2];
        ap[3] = lacc[threadIdx.x * 5 + 3];
        ap[4] = lacc[threadIdx.x * 5 + 4];
    }
}

// ---------------- fallback edge kernels (round-1 style, used if ws too small) ----------------
__global__ __launch_bounds__(256) void fb_stats1(const int* __restrict__ idx, const float4* __restrict__ h,
                                                 const float* __restrict__ w1, const float* __restrict__ b1,
                                                 float* __restrict__ sums, float* __restrict__ acc, int E_) {
    float a[16];
#pragma unroll
    for (int i = 0; i < 16; ++i) a[i] = 0.f;
    int stride = gridDim.x * blockDim.x;
    for (int e = blockIdx.x * blockDim.x + threadIdx.x; e < E_; e += stride) {
        int s = idx[e], d = idx[E_ + e];
        float4 hi = h[d], hj = h[s];
        float z[8];
        z1_of(hi, hj, w1, b1, z);
#pragma unroll
        for (int j = 0; j < 8; ++j) { a[j] += z[j]; a[8 + j] += z[j] * z[j]; }
        atomicAdd(acc + 8 * (size_t)d + 4, 1.0f);
    }
    block_reduce_atomics<16>(a, sums);
}

__global__ __launch_bounds__(256) void fb_stats2(const int* __restrict__ idx, const float4* __restrict__ h,
                                                 const float* __restrict__ w1, const float* __restrict__ b1,
                                                 const float* __restrict__ ss1,
                                                 const float* __restrict__ w2, const float* __restrict__ b2,
                                                 float* __restrict__ sums2, int E_) {
    float a[8];
#pragma unroll
    for (int i = 0; i < 8; ++i) a[i] = 0.f;
    int stride = gridDim.x * blockDim.x;
    for (int e = blockIdx.x * blockDim.x + threadIdx.x; e < E_; e += stride) {
        int s = idx[e], d = idx[E_ + e];
        float4 hi = h[d], hj = h[s];
        float z[8], m1[8], z2[4];
        z1_of(hi, hj, w1, b1, z);
#pragma unroll
        for (int j = 0; j < 8; ++j) m1[j] = ftanh(z[j] * ss1[j] + ss1[8 + j]);
        mat8x4(m1, w2, b2, z2);
#pragma unroll
        for (int c = 0; c < 4; ++c) { a[c] += z2[c]; a[4 + c] += z2[c] * z2[c]; }
    }
    block_reduce_atomics<8>(a, sums2);
}

__global__ __launch_bounds__(256) void fb_scatter(const int* __restrict__ idx, const float4* __restrict__ h,
                                                  const float* __restrict__ w1, const float* __restrict__ b1,
                                                  const float* __restrict__ ss1,
                                                  const float* __restrict__ w2, const float* __restrict__ b2,
                                                  const float* __restrict__ ss2,
                                                  float* __restrict__ acc, int E_) {
    int stride = gridDim.x * blockDim.x;
    for (int e = blockIdx.x * blockDim.x + threadIdx.x; e < E_; e += stride) {
        int s = idx[e], d = idx[E_ + e];
        float4 hi = h[d], hj = h[s];
        bool zero = (hi.x == hj.x) && (hi.y == hj.y) && (hi.z == hj.z) && (hi.w == hj.w);
        if (zero) continue;
        float z[8], m1[8], z2[4], m2[4];
        z1_of(hi, hj, w1, b1, z);
#pragma unroll
        for (int j = 0; j < 8; ++j) m1[j] = ftanh(z[j] * ss1[j] + ss1[8 + j]);
        mat8x4(m1, w2, b2, z2);
#pragma unroll
        for (int c = 0; c < 4; ++c) m2[c] = ftanh(z2[c] * ss2[c] + ss2[4 + c]);
        float* ap = acc + 8 * (size_t)d;
        atomicAdd(ap + 0, m2[0]);
        atomicAdd(ap + 1, m2[1]);
        atomicAdd(ap + 2, m2[2]);
        atomicAdd(ap + 3, m2[3]);
    }
}

// ---------------- node update MLP ----------------
__device__ __forceinline__ void load_u(int i, const float4* __restrict__ h,
                                       const float* __restrict__ acc, float* u) {
    float4 hv = h[i];
    const float* ap = acc + 8 * (size_t)i;
    float c = fmaxf(ap[4], 1.0f);
    u[0] = hv.x; u[1] = hv.y; u[2] = hv.z; u[3] = hv.w;
    u[4] = ap[0]; u[5] = ap[1]; u[6] = ap[2] / c; u[7] = ap[3] / c;
}

__global__ __launch_bounds__(256) void n_stats1(const float4* __restrict__ h,
                                                const float* __restrict__ acc,
                                                const float* __restrict__ w, const float* __restrict__ b,
                                                float* __restrict__ sums, int n) {
    float a[16];
#pragma unroll
    for (int i = 0; i < 16; ++i) a[i] = 0.f;
    int stride = gridDim.x * blockDim.x;
    for (int i = blockIdx.x * blockDim.x + threadIdx.x; i < n; i += stride) {
        float u[8], z[8];
        load_u(i, h, acc, u);
        mat8x8(u, w, b, z);
#pragma unroll
        for (int j = 0; j < 8; ++j) { a[j] += z[j]; a[8 + j] += z[j] * z[j]; }
    }
    block_reduce_atomics<16>(a, sums);
}

__global__ __launch_bounds__(256) void n_stats2(const float4* __restrict__ h,
                                                const float* __restrict__ acc,
                                                const float* __restrict__ w1, const float* __restrict__ b1,
                                                const float* __restrict__ ss3,
                                                const float* __restrict__ w2, const float* __restrict__ b2,
                                                float* __restrict__ sums, int n) {
    float a[8];
#pragma unroll
    for (int i = 0; i < 8; ++i) a[i] = 0.f;
    int stride = gridDim.x * blockDim.x;
    for (int i = blockIdx.x * blockDim.x + threadIdx.x; i < n; i += stride) {
        float u[8], z[8], u1[8], z4[4];
        load_u(i, h, acc, u);
        mat8x8(u, w1, b1, z);
#pragma unroll
        for (int j = 0; j < 8; ++j) u1[j] = ftanh(z[j] * ss3[j] + ss3[8 + j]);
        mat8x4(u1, w2, b2, z4);
#pragma unroll
        for (int c = 0; c < 4; ++c) { a[c] += z4[c]; a[4 + c] += z4[c] * z4[c]; }
    }
    block_reduce_atomics<8>(a, sums);
}

__global__ __launch_bounds__(256) void n_final(const float4* __restrict__ h,
                                               const float* __restrict__ acc,
                                               const float* __restrict__ w1, const float* __restrict__ b1,
                                               const float* __restrict__ ss3,
                                               const float* __restrict__ w2, const float* __restrict__ b2,
                                               const float* __restrict__ ss4,
                                               const float* __restrict__ pw, const float* __restrict__ pb,
                                               float2* __restrict__ out, int n) {
    int stride = gridDim.x * blockDim.x;
    for (int i = blockIdx.x * blockDim.x + threadIdx.x; i < n; i += stride) {
        float u[8], z[8], u1[8], z4[4], u2[4];
        load_u(i, h, acc, u);
        mat8x8(u, w1, b1, z);
#pragma unroll
        for (int j = 0; j < 8; ++j) u1[j] = ftanh(z[j] * ss3[j] + ss3[8 + j]);
        mat8x4(u1, w2, b2, z4);
#pragma unroll
        for (int c = 0; c < 4; ++c) u2[c] = ftanh(z4[c] * ss4[c] + ss4[4 + c]);
        float o0 = pb[0] + u2[0] * pw[0] + u2[1] * pw[2] + u2[2] * pw[4] + u2[3] * pw[6];
        float o1 = pb[1] + u2[0] * pw[1] + u2[1] * pw[3] + u2[2] * pw[5] + u2[3] * pw[7];
        out[i] = make_float2(o0, o1);
    }
}

extern "C" void kernel_launch(void* const* d_in, const int* in_sizes, int n_in,
                              void* d_out, int out_size, void* d_ws, size_t ws_size,
                              hipStream_t stream) {
    const float* pos  = (const float*)d_in[0];
    const float* vel  = (const float*)d_in[1];
    const int*   eidx = (const int*)d_in[2];
    const float* lin_w = (const float*)d_in[3];
    const float* lin_b = (const float*)d_in[4];
    const float* mw1 = (const float*)d_in[5];
    const float* mb1 = (const float*)d_in[6];
    const float* mg1 = (const float*)d_in[7];
    const float* mbe1 = (const float*)d_in[8];
    const float* mw2 = (const float*)d_in[9];
    const float* mb2 = (const float*)d_in[10];
    const float* mg2 = (const float*)d_in[11];
    const float* mbe2 = (const float*)d_in[12];
    const float* uw1 = (const float*)d_in[13];
    const float* ub1 = (const float*)d_in[14];
    const float* ug1 = (const float*)d_in[15];
    const float* ube1 = (const float*)d_in[16];
    const float* uw2 = (const float*)d_in[17];
    const float* ub2 = (const float*)d_in[18];
    const float* ug2 = (const float*)d_in[19];
    const float* ube2 = (const float*)d_in[20];
    const float* pw = (const float*)d_in[21];
    const float* pb = (const float*)d_in[22];

    int n  = in_sizes[0] / 2;
    int E_ = in_sizes[2] / 2;

    // ---- workspace layout (manual bump allocator, 16B aligned) ----
    char* base = (char*)d_ws;
    size_t off = 0;
    auto alloc = [&](size_t bytes) {
        off = (off + 15) & ~(size_t)15;
        void* p = base + off;
        off += bytes;
        return p;
    };
    float4*  h      = (float4*)alloc(16 * (size_t)n);
    float*   acc    = (float*)alloc(32 * (size_t)n);          // 8 floats/node {add0,add1,sum0,sum1,cnt,...}
    float*   sums   = (float*)alloc(256);                     // 64 stat sums
    float*   ss     = sums + 64;                              //  (second half of the 256B)
    uint32*  bbase  = (uint32*)alloc(4 * (NB + 1));
    uint32*  rowtot = (uint32*)alloc(4 * NB);
    uint32*  cntmat = (uint32*)alloc(4 * (size_t)NB * GB);
    unsigned char* ids = (unsigned char*)alloc((size_t)E_);
    vf4*     rec    = (vf4*)alloc(32 * (size_t)E_);
    size_t need_sort = off;

    bool big = ws_size >= need_sort;

    int nblk = (n + 255) / 256;
    int nbuckets = (n + 255) >> 8;
    int T = (E_ + GB - 1) / GB;

    k_h<<<nblk, 256, 0, stream>>>(pos, vel, lin_w, lin_b, h, n);

    if (big) {
        // stats sums zeroed; acc fully written by e_aggr (no memset needed)
        hipMemsetAsync(sums, 0, 256, stream);

        k_cnt<<<GB, 256, 0, stream>>>(eidx + E_, cntmat, E_, T);
        k_scanA<<<NB, 256, 0, stream>>>(cntmat, rowtot);
        k_scanB<<<1, 256, 0, stream>>>(rowtot, bbase);

        k_reorder<<<GB, 256, 0, stream>>>(eidx, h, mw1, mb1, cntmat, bbase, rec, ids, sums, E_, T);
        k_fin<<<1, 64, 0, stream>>>(sums, ss, mg1, mbe1, 8, 1.0f / (float)E_);

        e_pass2<<<4096, 256, 0, stream>>>(rec, mw1, mb1, ss, mw2, mb2, sums + 16, E_);
        k_fin<<<1, 64, 0, stream>>>(sums + 16, ss + 16, mg2, mbe2, 4, 1.0f / (float)E_);

        e_aggr<<<nbuckets, 256, 0, stream>>>(rec, ids, bbase, rowtot,
                                             mw1, mb1, ss, mw2, mb2, ss + 16, acc, n);
    } else {
        hipMemsetAsync(acc, 0, 32 * (size_t)n + 256, stream);  // acc + sums/ss contiguous

        fb_stats1<<<4096, 256, 0, stream>>>(eidx, h, mw1, mb1, sums, acc, E_);
        k_fin<<<1, 64, 0, stream>>>(sums, ss, mg1, mbe1, 8, 1.0f / (float)E_);

        fb_stats2<<<4096, 256, 0, stream>>>(eidx, h, mw1, mb1, ss, mw2, mb2, sums + 16, E_);
        k_fin<<<1, 64, 0, stream>>>(sums + 16, ss + 16, mg2, mbe2, 4, 1.0f / (float)E_);

        fb_scatter<<<4096, 256, 0, stream>>>(eidx, h, mw1, mb1, ss, mw2, mb2, ss + 16, acc, E_);
    }

    n_stats1<<<nblk, 256, 0, stream>>>(h, acc, uw1, ub1, sums + 24, n);
    k_fin<<<1, 64, 0, stream>>>(sums + 24, ss + 24, ug1, ube1, 8, 1.0f / (float)n);

    n_stats2<<<nblk, 256, 0, stream>>>(h, acc, uw1, ub1, ss + 24, uw2, ub2, sums + 40, n);
    k_fin<<<1, 64, 0, stream>>>(sums + 40, ss + 40, ug2, ube2, 4, 1.0f / (float)n);

    n_final<<<nblk, 256, 0, stream>>>(h, acc, uw1, ub1, ss + 24, uw2, ub2, ss + 40,
                                      pw, pb, (float2*)d_out, n);
}

// Round 7
// 882.467 us; speedup vs baseline: 2.4316x; 2.4316x over previous
//
#include <hip/hip_runtime.h>

#define EPSBN 1e-5f
#define NB 1024           // buckets (dst >> 8), 256 nodes per bucket
#define GB 1024           // blocks for cnt/reorder tiles

typedef float vf4 __attribute__((ext_vector_type(4)));
typedef unsigned int uint32;

__device__ __forceinline__ float ftanh(float x) {
    return 1.0f - 2.0f / (__expf(2.0f * x) + 1.0f);
}

__device__ __forceinline__ float wave_sum(float v) {
#pragma unroll
    for (int off = 32; off > 0; off >>= 1) v += __shfl_down(v, off);
    return v;
}

__device__ __forceinline__ void z1_of(const float4 hi, const float4 hj,
                                      const float* __restrict__ w, const float* __restrict__ b,
                                      float* z) {
#pragma unroll
    for (int j = 0; j < 8; ++j) {
        z[j] = b[j]
             + hi.x * w[0 * 8 + j] + hi.y * w[1 * 8 + j] + hi.z * w[2 * 8 + j] + hi.w * w[3 * 8 + j]
             + hj.x * w[4 * 8 + j] + hj.y * w[5 * 8 + j] + hj.z * w[6 * 8 + j] + hj.w * w[7 * 8 + j];
    }
}

__device__ __forceinline__ void mat8x8(const float* u, const float* __restrict__ w,
                                       const float* __restrict__ b, float* z) {
#pragma unroll
    for (int j = 0; j < 8; ++j) {
        float t = b[j];
#pragma unroll
        for (int k = 0; k < 8; ++k) t += u[k] * w[k * 8 + j];
        z[j] = t;
    }
}

__device__ __forceinline__ void mat8x4(const float* u, const float* __restrict__ w,
                                       const float* __restrict__ b, float* z) {
#pragma unroll
    for (int c = 0; c < 4; ++c) {
        float t = b[c];
#pragma unroll
        for (int k = 0; k < 8; ++k) t += u[k] * w[k * 4 + c];
        z[c] = t;
    }
}

template <int NV>
__device__ __forceinline__ void block_reduce_atomics(float* a, float* __restrict__ sums) {
    __shared__ float red[NV * 4];
    int wid = threadIdx.x >> 6, lane = threadIdx.x & 63;
#pragma unroll
    for (int i = 0; i < NV; ++i) {
        float v = wave_sum(a[i]);
        if (lane == 0) red[i * 4 + wid] = v;
    }
    __syncthreads();
    if (threadIdx.x < NV) {
        float v = red[threadIdx.x * 4 + 0] + red[threadIdx.x * 4 + 1]
                + red[threadIdx.x * 4 + 2] + red[threadIdx.x * 4 + 3];
        atomicAdd(&sums[threadIdx.x], v);
    }
}

// ---------------- node input projection ----------------
__global__ __launch_bounds__(256) void k_h(const float* __restrict__ pos, const float* __restrict__ vel,
                                           const float* __restrict__ w, const float* __restrict__ b,
                                           float4* __restrict__ h, int n) {
    int i = blockIdx.x * blockDim.x + threadIdx.x;
    if (i >= n) return;
    float2 p = ((const float2*)pos)[i];
    float2 v = ((const float2*)vel)[i];
    float o[4];
#pragma unroll
    for (int d = 0; d < 4; ++d)
        o[d] = b[d] + p.x * w[0 * 4 + d] + p.y * w[1 * 4 + d] + v.x * w[2 * 4 + d] + v.y * w[3 * 4 + d];
    h[i] = make_float4(o[0], o[1], o[2], o[3]);
}

// ---------------- count: per-(block,bucket) histogram, LDS atomics only ----------------
__global__ __launch_bounds__(256) void k_cnt(const int* __restrict__ dst, uint32* __restrict__ cntmat,
                                             int E_, int T) {
    __shared__ uint32 hist[NB];
    for (int b = threadIdx.x; b < NB; b += 256) hist[b] = 0;
    __syncthreads();
    int lo = blockIdx.x * T, hi2 = min(E_, lo + T);
    for (int e = lo + threadIdx.x; e < hi2; e += 256) {
        int d = __builtin_nontemporal_load(dst + e);
        atomicAdd(&hist[d >> 8], 1u);
    }
    __syncthreads();
    for (int b = threadIdx.x; b < NB; b += 256)
        cntmat[(size_t)b * GB + blockIdx.x] = hist[b];
}

// block-scan of 1024 uints (256 threads x 4), exclusive
__device__ __forceinline__ void scan1024(uint32* v, uint32* excl_out, uint32* total) {
    __shared__ uint32 ts[256];
    uint32 local = v[0] + v[1] + v[2] + v[3];
    ts[threadIdx.x] = local;
    __syncthreads();
    for (int off = 1; off < 256; off <<= 1) {
        uint32 t = (threadIdx.x >= (uint32)off) ? ts[threadIdx.x - off] : 0u;
        __syncthreads();
        ts[threadIdx.x] += t;
        __syncthreads();
    }
    *excl_out = ts[threadIdx.x] - local;
    *total = ts[255];
}

__global__ __launch_bounds__(256) void k_scanA(uint32* __restrict__ cntmat, uint32* __restrict__ rowtot) {
    size_t base = (size_t)blockIdx.x * GB + threadIdx.x * 4;
    uint32 v[4];
#pragma unroll
    for (int k = 0; k < 4; ++k) v[k] = cntmat[base + k];
    uint32 excl, tot;
    scan1024(v, &excl, &tot);
    uint32 run = excl;
#pragma unroll
    for (int k = 0; k < 4; ++k) { uint32 t = v[k]; cntmat[base + k] = run; run += t; }
    if (threadIdx.x == 0) rowtot[blockIdx.x] = tot;
}

__global__ __launch_bounds__(256) void k_scanB(const uint32* __restrict__ rowtot, uint32* __restrict__ bbase) {
    uint32 v[4];
#pragma unroll
    for (int k = 0; k < 4; ++k) v[k] = rowtot[threadIdx.x * 4 + k];
    uint32 excl, tot;
    scan1024(v, &excl, &tot);
    uint32 run = excl;
#pragma unroll
    for (int k = 0; k < 4; ++k) { uint32 t = v[k]; bbase[threadIdx.x * 4 + k] = run; run += t; }
    if (threadIdx.x == 0) bbase[NB] = tot;
}

// ---------------- reorder + gather + z1 stats (LDS cursors, no global atomics) ----------------
// writes per edge: rec[pos] = h_j (16B), dsts[pos] = dst (4B)
__global__ __launch_bounds__(256) void k_reorder(const int* __restrict__ idx, const float4* __restrict__ h,
                                                 const float* __restrict__ w1, const float* __restrict__ b1,
                                                 const uint32* __restrict__ cntmat, const uint32* __restrict__ bbase,
                                                 vf4* __restrict__ rec, int* __restrict__ dsts,
                                                 float* __restrict__ sums, int E_, int T) {
    __shared__ uint32 cur[NB];
    for (int b = threadIdx.x; b < NB; b += 256)
        cur[b] = bbase[b] + cntmat[(size_t)b * GB + blockIdx.x];
    float a[16];
#pragma unroll
    for (int i = 0; i < 16; ++i) a[i] = 0.f;
    __syncthreads();
    int lo = blockIdx.x * T, hi2 = min(E_, lo + T);
    for (int e = lo + threadIdx.x; e < hi2; e += 256) {
        int s = __builtin_nontemporal_load(idx + e);
        int d = __builtin_nontemporal_load(idx + E_ + e);
        float4 hi = h[d], hj = h[s];
        float z[8];
        z1_of(hi, hj, w1, b1, z);
#pragma unroll
        for (int j = 0; j < 8; ++j) { a[j] += z[j]; a[8 + j] += z[j] * z[j]; }
        uint32 pos = atomicAdd(&cur[d >> 8], 1u);
        vf4 vj = {hj.x, hj.y, hj.z, hj.w};
        rec[pos] = vj;
        dsts[pos] = d;
    }
    block_reduce_atomics<16>(a, sums);
}

// ---------------- finalize BN stats -> scale/shift ----------------
__global__ void k_fin(const float* __restrict__ sums, float* __restrict__ ss,
                      const float* __restrict__ g, const float* __restrict__ be,
                      int d, float inv_count) {
    int j = threadIdx.x;
    if (j >= d) return;
    float mu = sums[j] * inv_count;
    float var = sums[d + j] * inv_count - mu * mu;
    float s = g[j] * rsqrtf(var + EPSBN);
    ss[j] = s;
    ss[d + j] = be[j] - mu * s;
}

// ---------------- E2: stream sorted rec; h[dst] gathers are window-local (cached) ----------------
__global__ __launch_bounds__(256) void e_pass2(const vf4* __restrict__ rec, const int* __restrict__ dsts,
                                               const float4* __restrict__ h,
                                               const float* __restrict__ w1, const float* __restrict__ b1,
                                               const float* __restrict__ ss1,
                                               const float* __restrict__ w2, const float* __restrict__ b2,
                                               float* __restrict__ sums2, int E_) {
    float a[8];
#pragma unroll
    for (int i = 0; i < 8; ++i) a[i] = 0.f;
    int stride = gridDim.x * blockDim.x;
    for (int e = blockIdx.x * blockDim.x + threadIdx.x; e < E_; e += stride) {
        vf4 vj = __builtin_nontemporal_load(&rec[e]);
        int d = __builtin_nontemporal_load(dsts + e);
        float4 hi = h[d];
        float4 hj = make_float4(vj.x, vj.y, vj.z, vj.w);
        float z[8], m1[8], z2[4];
        z1_of(hi, hj, w1, b1, z);
#pragma unroll
        for (int j = 0; j < 8; ++j) m1[j] = ftanh(z[j] * ss1[j] + ss1[8 + j]);
        mat8x4(m1, w2, b2, z2);
#pragma unroll
        for (int c = 0; c < 4; ++c) { a[c] += z2[c]; a[4 + c] += z2[c] * z2[c]; }
    }
    block_reduce_atomics<8>(a, sums2);
}

// ---------------- aggregate: one block per bucket; h staged in LDS; LDS atomics only ----------------
__global__ __launch_bounds__(256) void e_aggr(const vf4* __restrict__ rec, const int* __restrict__ dsts,
                                              const float4* __restrict__ h,
                                              const uint32* __restrict__ bbase, const uint32* __restrict__ rowtot,
                                              const float* __restrict__ w1, const float* __restrict__ b1,
                                              const float* __restrict__ ss1,
                                              const float* __restrict__ w2, const float* __restrict__ b2,
                                              const float* __restrict__ ss2,
                                              float* __restrict__ acc, int n) {
    __shared__ float lacc[256 * 5];
    __shared__ float4 hloc[256];
    int nodebase = blockIdx.x << 8;
    for (int k = threadIdx.x; k < 256 * 5; k += 256) lacc[k] = 0.f;
    {
        int node = nodebase + threadIdx.x;
        hloc[threadIdx.x] = (node < n) ? h[node] : make_float4(0.f, 0.f, 0.f, 0.f);
    }
    __syncthreads();
    uint32 start = bbase[blockIdx.x];
    uint32 end = start + rowtot[blockIdx.x];
    for (uint32 e = start + threadIdx.x; e < end; e += 256) {
        vf4 vj = __builtin_nontemporal_load(&rec[e]);
        int id = __builtin_nontemporal_load(dsts + e) - nodebase;
        float4 hi = hloc[id];
        bool zero = (hi.x == vj.x) && (hi.y == vj.y) && (hi.z == vj.z) && (hi.w == vj.w);
        if (!zero) {
            float4 hj = make_float4(vj.x, vj.y, vj.z, vj.w);
            float z[8], m1[8], z2[4], m2[4];
            z1_of(hi, hj, w1, b1, z);
#pragma unroll
            for (int j = 0; j < 8; ++j) m1[j] = ftanh(z[j] * ss1[j] + ss1[8 + j]);
            mat8x4(m1, w2, b2, z2);
#pragma unroll
            for (int c = 0; c < 4; ++c) m2[c] = ftanh(z2[c] * ss2[c] + ss2[4 + c]);
#pragma unroll
            for (int c = 0; c < 4; ++c) atomicAdd(&lacc[id * 5 + c], m2[c]);
        }
        atomicAdd(&lacc[id * 5 + 4], 1.0f);
    }
    __syncthreads();
    int node = nodebase + threadIdx.x;
    if (node < n) {
        float* ap = acc + 8 * (size_t)node;
        ap[0] = lacc[threadIdx.x * 5 + 0];
        ap[1] = lacc[threadIdx.x * 5 + 1];
        ap[2] = lacc[threadIdx.x * 5 + 2];
        ap[3] = lacc[threadIdx.x * 5 + 3];
        ap[4] = lacc[threadIdx.x * 5 + 4];
    }
}

// ---------------- fallback edge kernels (round-1 style, used if ws too small) ----------------
__global__ __launch_bounds__(256) void fb_stats1(const int* __restrict__ idx, const float4* __restrict__ h,
                                                 const float* __restrict__ w1, const float* __restrict__ b1,
                                                 float* __restrict__ sums, float* __restrict__ acc, int E_) {
    float a[16];
#pragma unroll
    for (int i = 0; i < 16; ++i) a[i] = 0.f;
    int stride = gridDim.x * blockDim.x;
    for (int e = blockIdx.x * blockDim.x + threadIdx.x; e < E_; e += stride) {
        int s = __builtin_nontemporal_load(idx + e);
        int d = __builtin_nontemporal_load(idx + E_ + e);
        float4 hi = h[d], hj = h[s];
        float z[8];
        z1_of(hi, hj, w1, b1, z);
#pragma unroll
        for (int j = 0; j < 8; ++j) { a[j] += z[j]; a[8 + j] += z[j] * z[j]; }
        atomicAdd(acc + 8 * (size_t)d + 4, 1.0f);
    }
    block_reduce_atomics<16>(a, sums);
}

__global__ __launch_bounds__(256) void fb_stats2(const int* __restrict__ idx, const float4* __restrict__ h,
                                                 const float* __restrict__ w1, const float* __restrict__ b1,
                                                 const float* __restrict__ ss1,
                                                 const float* __restrict__ w2, const float* __restrict__ b2,
                                                 float* __restrict__ sums2, int E_) {
    float a[8];
#pragma unroll
    for (int i = 0; i < 8; ++i) a[i] = 0.f;
    int stride = gridDim.x * blockDim.x;
    for (int e = blockIdx.x * blockDim.x + threadIdx.x; e < E_; e += stride) {
        int s = __builtin_nontemporal_load(idx + e);
        int d = __builtin_nontemporal_load(idx + E_ + e);
        float4 hi = h[d], hj = h[s];
        float z[8], m1[8], z2[4];
        z1_of(hi, hj, w1, b1, z);
#pragma unroll
        for (int j = 0; j < 8; ++j) m1[j] = ftanh(z[j] * ss1[j] + ss1[8 + j]);
        mat8x4(m1, w2, b2, z2);
#pragma unroll
        for (int c = 0; c < 4; ++c) { a[c] += z2[c]; a[4 + c] += z2[c] * z2[c]; }
    }
    block_reduce_atomics<8>(a, sums2);
}

__global__ __launch_bounds__(256) void fb_scatter(const int* __restrict__ idx, const float4* __restrict__ h,
                                                  const float* __restrict__ w1, const float* __restrict__ b1,
                                                  const float* __restrict__ ss1,
                                                  const float* __restrict__ w2, const float* __restrict__ b2,
                                                  const float* __restrict__ ss2,
                                                  float* __restrict__ acc, int E_) {
    int stride = gridDim.x * blockDim.x;
    for (int e = blockIdx.x * blockDim.x + threadIdx.x; e < E_; e += stride) {
        int s = __builtin_nontemporal_load(idx + e);
        int d = __builtin_nontemporal_load(idx + E_ + e);
        float4 hi = h[d], hj = h[s];
        bool zero = (hi.x == hj.x) && (hi.y == hj.y) && (hi.z == hj.z) && (hi.w == hj.w);
        if (zero) continue;
        float z[8], m1[8], z2[4], m2[4];
        z1_of(hi, hj, w1, b1, z);
#pragma unroll
        for (int j = 0; j < 8; ++j) m1[j] = ftanh(z[j] * ss1[j] + ss1[8 + j]);
        mat8x4(m1, w2, b2, z2);
#pragma unroll
        for (int c = 0; c < 4; ++c) m2[c] = ftanh(z2[c] * ss2[c] + ss2[4 + c]);
        float* ap = acc + 8 * (size_t)d;
        atomicAdd(ap + 0, m2[0]);
        atomicAdd(ap + 1, m2[1]);
        atomicAdd(ap + 2, m2[2]);
        atomicAdd(ap + 3, m2[3]);
    }
}

// ---------------- node update MLP ----------------
__device__ __forceinline__ void load_u(int i, const float4* __restrict__ h,
                                       const float* __restrict__ acc, float* u) {
    float4 hv = h[i];
    const float* ap = acc + 8 * (size_t)i;
    float c = fmaxf(ap[4], 1.0f);
    u[0] = hv.x; u[1] = hv.y; u[2] = hv.z; u[3] = hv.w;
    u[4] = ap[0]; u[5] = ap[1]; u[6] = ap[2] / c; u[7] = ap[3] / c;
}

__global__ __launch_bounds__(256) void n_stats1(const float4* __restrict__ h,
                                                const float* __restrict__ acc,
                                                const float* __restrict__ w, const float* __restrict__ b,
                                                float* __restrict__ sums, int n) {
    float a[16];
#pragma unroll
    for (int i = 0; i < 16; ++i) a[i] = 0.f;
    int stride = gridDim.x * blockDim.x;
    for (int i = blockIdx.x * blockDim.x + threadIdx.x; i < n; i += stride) {
        float u[8], z[8];
        load_u(i, h, acc, u);
        mat8x8(u, w, b, z);
#pragma unroll
        for (int j = 0; j < 8; ++j) { a[j] += z[j]; a[8 + j] += z[j] * z[j]; }
    }
    block_reduce_atomics<16>(a, sums);
}

__global__ __launch_bounds__(256) void n_stats2(const float4* __restrict__ h,
                                                const float* __restrict__ acc,
                                                const float* __restrict__ w1, const float* __restrict__ b1,
                                                const float* __restrict__ ss3,
                                                const float* __restrict__ w2, const float* __restrict__ b2,
                                                float* __restrict__ sums, int n) {
    float a[8];
#pragma unroll
    for (int i = 0; i < 8; ++i) a[i] = 0.f;
    int stride = gridDim.x * blockDim.x;
    for (int i = blockIdx.x * blockDim.x + threadIdx.x; i < n; i += stride) {
        float u[8], z[8], u1[8], z4[4];
        load_u(i, h, acc, u);
        mat8x8(u, w1, b1, z);
#pragma unroll
        for (int j = 0; j < 8; ++j) u1[j] = ftanh(z[j] * ss3[j] + ss3[8 + j]);
        mat8x4(u1, w2, b2, z4);
#pragma unroll
        for (int c = 0; c < 4; ++c) { a[c] += z4[c]; a[4 + c] += z4[c] * z4[c]; }
    }
    block_reduce_atomics<8>(a, sums);
}

__global__ __launch_bounds__(256) void n_final(const float4* __restrict__ h,
                                               const float* __restrict__ acc,
                                               const float* __restrict__ w1, const float* __restrict__ b1,
                                               const float* __restrict__ ss3,
                                               const float* __restrict__ w2, const float* __restrict__ b2,
                                               const float* __restrict__ ss4,
                                               const float* __restrict__ pw, const float* __restrict__ pb,
                                               float2* __restrict__ out, int n) {
    int stride = gridDim.x * blockDim.x;
    for (int i = blockIdx.x * blockDim.x + threadIdx.x; i < n; i += stride) {
        float u[8], z[8], u1[8], z4[4], u2[4];
        load_u(i, h, acc, u);
        mat8x8(u, w1, b1, z);
#pragma unroll
        for (int j = 0; j < 8; ++j) u1[j] = ftanh(z[j] * ss3[j] + ss3[8 + j]);
        mat8x4(u1, w2, b2, z4);
#pragma unroll
        for (int c = 0; c < 4; ++c) u2[c] = ftanh(z4[c] * ss4[c] + ss4[4 + c]);
        float o0 = pb[0] + u2[0] * pw[0] + u2[1] * pw[2] + u2[2] * pw[4] + u2[3] * pw[6];
        float o1 = pb[1] + u2[0] * pw[1] + u2[1] * pw[3] + u2[2] * pw[5] + u2[3] * pw[7];
        out[i] = make_float2(o0, o1);
    }
}

extern "C" void kernel_launch(void* const* d_in, const int* in_sizes, int n_in,
                              void* d_out, int out_size, void* d_ws, size_t ws_size,
                              hipStream_t stream) {
    const float* pos  = (const float*)d_in[0];
    const float* vel  = (const float*)d_in[1];
    const int*   eidx = (const int*)d_in[2];
    const float* lin_w = (const float*)d_in[3];
    const float* lin_b = (const float*)d_in[4];
    const float* mw1 = (const float*)d_in[5];
    const float* mb1 = (const float*)d_in[6];
    const float* mg1 = (const float*)d_in[7];
    const float* mbe1 = (const float*)d_in[8];
    const float* mw2 = (const float*)d_in[9];
    const float* mb2 = (const float*)d_in[10];
    const float* mg2 = (const float*)d_in[11];
    const float* mbe2 = (const float*)d_in[12];
    const float* uw1 = (const float*)d_in[13];
    const float* ub1 = (const float*)d_in[14];
    const float* ug1 = (const float*)d_in[15];
    const float* ube1 = (const float*)d_in[16];
    const float* uw2 = (const float*)d_in[17];
    const float* ub2 = (const float*)d_in[18];
    const float* ug2 = (const float*)d_in[19];
    const float* ube2 = (const float*)d_in[20];
    const float* pw = (const float*)d_in[21];
    const float* pb = (const float*)d_in[22];

    int n  = in_sizes[0] / 2;
    int E_ = in_sizes[2] / 2;

    // ---- workspace layout (bump allocator, 16B aligned) ----
    char* base = (char*)d_ws;
    size_t off = 0;
    auto alloc = [&](size_t bytes) {
        off = (off + 15) & ~(size_t)15;
        void* p = base + off;
        off += bytes;
        return p;
    };
    float4*  h      = (float4*)alloc(16 * (size_t)n);         // 4 MB
    float*   acc    = (float*)alloc(32 * (size_t)n);          // 8 MB
    float*   sums   = (float*)alloc(512);                     // 64 stat sums + 64 scale/shift (FIX: was 256)
    float*   ss     = sums + 64;
    uint32*  bbase  = (uint32*)alloc(4 * (NB + 1));
    uint32*  rowtot = (uint32*)alloc(4 * NB);
    uint32*  cntmat = (uint32*)alloc(4 * (size_t)NB * GB);    // 4 MB
    int*     dsts   = (int*)alloc(4 * (size_t)E_);            // 32 MB
    vf4*     rec    = (vf4*)alloc(16 * (size_t)E_);           // 128 MB
    size_t need_sort = off;                                    // ~176 MB

    bool big = ws_size >= need_sort;

    int nblk = (n + 255) / 256;
    int nbuckets = (n + 255) >> 8;
    int T = (E_ + GB - 1) / GB;

    k_h<<<nblk, 256, 0, stream>>>(pos, vel, lin_w, lin_b, h, n);

    if (big) {
        (void)hipMemsetAsync(sums, 0, 256, stream);   // zero the 64 accumulator floats

        k_cnt<<<GB, 256, 0, stream>>>(eidx + E_, cntmat, E_, T);
        k_scanA<<<NB, 256, 0, stream>>>(cntmat, rowtot);
        k_scanB<<<1, 256, 0, stream>>>(rowtot, bbase);

        k_reorder<<<GB, 256, 0, stream>>>(eidx, h, mw1, mb1, cntmat, bbase, rec, dsts, sums, E_, T);
        k_fin<<<1, 64, 0, stream>>>(sums, ss, mg1, mbe1, 8, 1.0f / (float)E_);

        e_pass2<<<4096, 256, 0, stream>>>(rec, dsts, h, mw1, mb1, ss, mw2, mb2, sums + 16, E_);
        k_fin<<<1, 64, 0, stream>>>(sums + 16, ss + 16, mg2, mbe2, 4, 1.0f / (float)E_);

        e_aggr<<<nbuckets, 256, 0, stream>>>(rec, dsts, h, bbase, rowtot,
                                             mw1, mb1, ss, mw2, mb2, ss + 16, acc, n);
    } else {
        (void)hipMemsetAsync(acc, 0, 32 * (size_t)n + 256, stream);

        fb_stats1<<<4096, 256, 0, stream>>>(eidx, h, mw1, mb1, sums, acc, E_);
        k_fin<<<1, 64, 0, stream>>>(sums, ss, mg1, mbe1, 8, 1.0f / (float)E_);

        fb_stats2<<<4096, 256, 0, stream>>>(eidx, h, mw1, mb1, ss, mw2, mb2, sums + 16, E_);
        k_fin<<<1, 64, 0, stream>>>(sums + 16, ss + 16, mg2, mbe2, 4, 1.0f / (float)E_);

        fb_scatter<<<4096, 256, 0, stream>>>(eidx, h, mw1, mb1, ss, mw2, mb2, ss + 16, acc, E_);
    }

    n_stats1<<<nblk, 256, 0, stream>>>(h, acc, uw1, ub1, sums + 24, n);
    k_fin<<<1, 64, 0, stream>>>(sums + 24, ss + 24, ug1, ube1, 8, 1.0f / (float)n);

    n_stats2<<<nblk, 256, 0, stream>>>(h, acc, uw1, ub1, ss + 24, uw2, ub2, sums + 40, n);
    k_fin<<<1, 64, 0, stream>>>(sums + 40, ss + 40, ug2, ube2, 4, 1.0f / (float)n);

    n_final<<<nblk, 256, 0, stream>>>(h, acc, uw1, ub1, ss + 24, uw2, ub2, ss + 40,
                                      pw, pb, (float2*)d_out, n);
}

// Round 8
// 844.852 us; speedup vs baseline: 2.5399x; 1.0445x over previous
//
#include <hip/hip_runtime.h>

#define EPSBN 1e-5f
#define NB 512            // buckets (dst >> 9), 512 nodes per bucket
#define GB 512            // blocks for cnt/reorder tiles

typedef float vf4 __attribute__((ext_vector_type(4)));
typedef unsigned int uint32;
typedef unsigned short ushort16;

__device__ __forceinline__ float ftanh(float x) {
    return 1.0f - 2.0f / (__expf(2.0f * x) + 1.0f);
}

__device__ __forceinline__ float wave_sum(float v) {
#pragma unroll
    for (int off = 32; off > 0; off >>= 1) v += __shfl_down(v, off);
    return v;
}

__device__ __forceinline__ void z1_of(const float4 hi, const float4 hj,
                                      const float* __restrict__ w, const float* __restrict__ b,
                                      float* z) {
#pragma unroll
    for (int j = 0; j < 8; ++j) {
        z[j] = b[j]
             + hi.x * w[0 * 8 + j] + hi.y * w[1 * 8 + j] + hi.z * w[2 * 8 + j] + hi.w * w[3 * 8 + j]
             + hj.x * w[4 * 8 + j] + hj.y * w[5 * 8 + j] + hj.z * w[6 * 8 + j] + hj.w * w[7 * 8 + j];
    }
}

__device__ __forceinline__ void mat8x8(const float* u, const float* __restrict__ w,
                                       const float* __restrict__ b, float* z) {
#pragma unroll
    for (int j = 0; j < 8; ++j) {
        float t = b[j];
#pragma unroll
        for (int k = 0; k < 8; ++k) t += u[k] * w[k * 8 + j];
        z[j] = t;
    }
}

__device__ __forceinline__ void mat8x4(const float* u, const float* __restrict__ w,
                                       const float* __restrict__ b, float* z) {
#pragma unroll
    for (int c = 0; c < 4; ++c) {
        float t = b[c];
#pragma unroll
        for (int k = 0; k < 8; ++k) t += u[k] * w[k * 4 + c];
        z[c] = t;
    }
}

template <int NV>
__device__ __forceinline__ void block_reduce_atomics(float* a, float* __restrict__ sums) {
    __shared__ float red[NV * 4];
    int wid = threadIdx.x >> 6, lane = threadIdx.x & 63;
#pragma unroll
    for (int i = 0; i < NV; ++i) {
        float v = wave_sum(a[i]);
        if (lane == 0) red[i * 4 + wid] = v;
    }
    __syncthreads();
    if (threadIdx.x < NV) {
        float v = red[threadIdx.x * 4 + 0] + red[threadIdx.x * 4 + 1]
                + red[threadIdx.x * 4 + 2] + red[threadIdx.x * 4 + 3];
        atomicAdd(&sums[threadIdx.x], v);
    }
}

// ---------------- node input projection ----------------
__global__ __launch_bounds__(256) void k_h(const float* __restrict__ pos, const float* __restrict__ vel,
                                           const float* __restrict__ w, const float* __restrict__ b,
                                           float4* __restrict__ h, int n) {
    int i = blockIdx.x * blockDim.x + threadIdx.x;
    if (i >= n) return;
    float2 p = ((const float2*)pos)[i];
    float2 v = ((const float2*)vel)[i];
    float o[4];
#pragma unroll
    for (int d = 0; d < 4; ++d)
        o[d] = b[d] + p.x * w[0 * 4 + d] + p.y * w[1 * 4 + d] + v.x * w[2 * 4 + d] + v.y * w[3 * 4 + d];
    h[i] = make_float4(o[0], o[1], o[2], o[3]);
}

// ---------------- count: per-(block,bucket) histogram, LDS atomics only ----------------
__global__ __launch_bounds__(256) void k_cnt(const int* __restrict__ dst, uint32* __restrict__ cntmat,
                                             int E_, int T) {
    __shared__ uint32 hist[NB];
    for (int b = threadIdx.x; b < NB; b += 256) hist[b] = 0;
    __syncthreads();
    int lo = blockIdx.x * T, hi2 = min(E_, lo + T);
    for (int e = lo + threadIdx.x; e < hi2; e += 256) {
        int d = __builtin_nontemporal_load(dst + e);
        atomicAdd(&hist[d >> 9], 1u);
    }
    __syncthreads();
    for (int b = threadIdx.x; b < NB; b += 256)
        cntmat[(size_t)b * GB + blockIdx.x] = hist[b];
}

// block-scan of 512 uints (256 threads x 2), exclusive
__device__ __forceinline__ void scan512(uint32* v, uint32* excl_out, uint32* total) {
    __shared__ uint32 ts[256];
    uint32 local = v[0] + v[1];
    ts[threadIdx.x] = local;
    __syncthreads();
    for (int off = 1; off < 256; off <<= 1) {
        uint32 t = (threadIdx.x >= (uint32)off) ? ts[threadIdx.x - off] : 0u;
        __syncthreads();
        ts[threadIdx.x] += t;
        __syncthreads();
    }
    *excl_out = ts[threadIdx.x] - local;
    *total = ts[255];
}

__global__ __launch_bounds__(256) void k_scanA(uint32* __restrict__ cntmat, uint32* __restrict__ rowtot) {
    size_t base = (size_t)blockIdx.x * GB + threadIdx.x * 2;
    uint32 v[2];
    v[0] = cntmat[base]; v[1] = cntmat[base + 1];
    uint32 excl, tot;
    scan512(v, &excl, &tot);
    cntmat[base] = excl;
    cntmat[base + 1] = excl + v[0];
    if (threadIdx.x == 0) rowtot[blockIdx.x] = tot;
}

__global__ __launch_bounds__(256) void k_scanB(const uint32* __restrict__ rowtot, uint32* __restrict__ bbase) {
    uint32 v[2];
    v[0] = rowtot[threadIdx.x * 2]; v[1] = rowtot[threadIdx.x * 2 + 1];
    uint32 excl, tot;
    scan512(v, &excl, &tot);
    bbase[threadIdx.x * 2] = excl;
    bbase[threadIdx.x * 2 + 1] = excl + v[0];
    if (threadIdx.x == 0) bbase[NB] = tot;
}

// ---------------- reorder + gather + z1 stats (LDS cursors, no global atomics) ----------------
// writes per edge: rec[pos] = h_j (16B), ids[pos] = dst & 511 (2B)
__global__ __launch_bounds__(256) void k_reorder(const int* __restrict__ idx, const float4* __restrict__ h,
                                                 const float* __restrict__ w1, const float* __restrict__ b1,
                                                 const uint32* __restrict__ cntmat, const uint32* __restrict__ bbase,
                                                 vf4* __restrict__ rec, ushort16* __restrict__ ids,
                                                 float* __restrict__ sums, int E_, int T) {
    __shared__ uint32 cur[NB];
    for (int b = threadIdx.x; b < NB; b += 256)
        cur[b] = bbase[b] + cntmat[(size_t)b * GB + blockIdx.x];
    float a[16];
#pragma unroll
    for (int i = 0; i < 16; ++i) a[i] = 0.f;
    __syncthreads();
    int lo = blockIdx.x * T, hi2 = min(E_, lo + T);
    for (int e = lo + threadIdx.x; e < hi2; e += 256) {
        int s = __builtin_nontemporal_load(idx + e);
        int d = __builtin_nontemporal_load(idx + E_ + e);
        float4 hi = h[d], hj = h[s];
        float z[8];
        z1_of(hi, hj, w1, b1, z);
#pragma unroll
        for (int j = 0; j < 8; ++j) { a[j] += z[j]; a[8 + j] += z[j] * z[j]; }
        uint32 pos = atomicAdd(&cur[d >> 9], 1u);
        vf4 vj = {hj.x, hj.y, hj.z, hj.w};
        rec[pos] = vj;
        ids[pos] = (ushort16)(d & 511);
    }
    block_reduce_atomics<16>(a, sums);
}

// ---------------- finalize BN stats -> scale/shift ----------------
__global__ void k_fin(const float* __restrict__ sums, float* __restrict__ ss,
                      const float* __restrict__ g, const float* __restrict__ be,
                      int d, float inv_count) {
    int j = threadIdx.x;
    if (j >= d) return;
    float mu = sums[j] * inv_count;
    float var = sums[d + j] * inv_count - mu * mu;
    float s = g[j] * rsqrtf(var + EPSBN);
    ss[j] = s;
    ss[d + j] = be[j] - mu * s;
}

// ---------------- E2: per-bucket stream of sorted rec; h_i from LDS ----------------
__global__ __launch_bounds__(256) void e_pass2(const vf4* __restrict__ rec, const ushort16* __restrict__ ids,
                                               const float4* __restrict__ h,
                                               const uint32* __restrict__ bbase, const uint32* __restrict__ rowtot,
                                               const float* __restrict__ w1, const float* __restrict__ b1,
                                               const float* __restrict__ ss1,
                                               const float* __restrict__ w2, const float* __restrict__ b2,
                                               float* __restrict__ sums2, int n) {
    __shared__ float4 hloc[512];
    int nodebase = blockIdx.x << 9;
    for (int k = threadIdx.x; k < 512; k += 256) {
        int node = nodebase + k;
        hloc[k] = (node < n) ? h[node] : make_float4(0.f, 0.f, 0.f, 0.f);
    }
    float a[8];
#pragma unroll
    for (int i = 0; i < 8; ++i) a[i] = 0.f;
    __syncthreads();
    uint32 start = bbase[blockIdx.x];
    uint32 end = start + rowtot[blockIdx.x];
    for (uint32 e = start + threadIdx.x; e < end; e += 256) {
        vf4 vj = __builtin_nontemporal_load(&rec[e]);
        int id = __builtin_nontemporal_load(&ids[e]);
        float4 hi = hloc[id];
        float4 hj = make_float4(vj.x, vj.y, vj.z, vj.w);
        float z[8], m1[8], z2[4];
        z1_of(hi, hj, w1, b1, z);
#pragma unroll
        for (int j = 0; j < 8; ++j) m1[j] = ftanh(z[j] * ss1[j] + ss1[8 + j]);
        mat8x4(m1, w2, b2, z2);
#pragma unroll
        for (int c = 0; c < 4; ++c) { a[c] += z2[c]; a[4 + c] += z2[c] * z2[c]; }
    }
    block_reduce_atomics<8>(a, sums2);
}

// ---------------- aggregate: one block per bucket; LDS accumulators; no global atomics ----------------
__global__ __launch_bounds__(256) void e_aggr(const vf4* __restrict__ rec, const ushort16* __restrict__ ids,
                                              const float4* __restrict__ h,
                                              const uint32* __restrict__ bbase, const uint32* __restrict__ rowtot,
                                              const float* __restrict__ w1, const float* __restrict__ b1,
                                              const float* __restrict__ ss1,
                                              const float* __restrict__ w2, const float* __restrict__ b2,
                                              const float* __restrict__ ss2,
                                              float* __restrict__ acc, int n) {
    __shared__ float lacc[512 * 5];
    __shared__ float4 hloc[512];
    int nodebase = blockIdx.x << 9;
    for (int k = threadIdx.x; k < 512 * 5; k += 256) lacc[k] = 0.f;
    for (int k = threadIdx.x; k < 512; k += 256) {
        int node = nodebase + k;
        hloc[k] = (node < n) ? h[node] : make_float4(0.f, 0.f, 0.f, 0.f);
    }
    __syncthreads();
    uint32 start = bbase[blockIdx.x];
    uint32 end = start + rowtot[blockIdx.x];
    for (uint32 e = start + threadIdx.x; e < end; e += 256) {
        vf4 vj = __builtin_nontemporal_load(&rec[e]);
        int id = __builtin_nontemporal_load(&ids[e]);
        float4 hi = hloc[id];
        bool zero = (hi.x == vj.x) && (hi.y == vj.y) && (hi.z == vj.z) && (hi.w == vj.w);
        if (!zero) {
            float4 hj = make_float4(vj.x, vj.y, vj.z, vj.w);
            float z[8], m1[8], z2[4], m2[4];
            z1_of(hi, hj, w1, b1, z);
#pragma unroll
            for (int j = 0; j < 8; ++j) m1[j] = ftanh(z[j] * ss1[j] + ss1[8 + j]);
            mat8x4(m1, w2, b2, z2);
#pragma unroll
            for (int c = 0; c < 4; ++c) m2[c] = ftanh(z2[c] * ss2[c] + ss2[4 + c]);
#pragma unroll
            for (int c = 0; c < 4; ++c) atomicAdd(&lacc[id * 5 + c], m2[c]);
        }
        atomicAdd(&lacc[id * 5 + 4], 1.0f);
    }
    __syncthreads();
    for (int k = threadIdx.x; k < 512; k += 256) {
        int node = nodebase + k;
        if (node < n) {
            float* ap = acc + 8 * (size_t)node;
            ap[0] = lacc[k * 5 + 0];
            ap[1] = lacc[k * 5 + 1];
            ap[2] = lacc[k * 5 + 2];
            ap[3] = lacc[k * 5 + 3];
            ap[4] = lacc[k * 5 + 4];
        }
    }
}

// ---------------- fallback edge kernels (round-1 style, used if ws too small) ----------------
__global__ __launch_bounds__(256) void fb_stats1(const int* __restrict__ idx, const float4* __restrict__ h,
                                                 const float* __restrict__ w1, const float* __restrict__ b1,
                                                 float* __restrict__ sums, float* __restrict__ acc, int E_) {
    float a[16];
#pragma unroll
    for (int i = 0; i < 16; ++i) a[i] = 0.f;
    int stride = gridDim.x * blockDim.x;
    for (int e = blockIdx.x * blockDim.x + threadIdx.x; e < E_; e += stride) {
        int s = __builtin_nontemporal_load(idx + e);
        int d = __builtin_nontemporal_load(idx + E_ + e);
        float4 hi = h[d], hj = h[s];
        float z[8];
        z1_of(hi, hj, w1, b1, z);
#pragma unroll
        for (int j = 0; j < 8; ++j) { a[j] += z[j]; a[8 + j] += z[j] * z[j]; }
        atomicAdd(acc + 8 * (size_t)d + 4, 1.0f);
    }
    block_reduce_atomics<16>(a, sums);
}

__global__ __launch_bounds__(256) void fb_stats2(const int* __restrict__ idx, const float4* __restrict__ h,
                                                 const float* __restrict__ w1, const float* __restrict__ b1,
                                                 const float* __restrict__ ss1,
                                                 const float* __restrict__ w2, const float* __restrict__ b2,
                                                 float* __restrict__ sums2, int E_) {
    float a[8];
#pragma unroll
    for (int i = 0; i < 8; ++i) a[i] = 0.f;
    int stride = gridDim.x * blockDim.x;
    for (int e = blockIdx.x * blockDim.x + threadIdx.x; e < E_; e += stride) {
        int s = __builtin_nontemporal_load(idx + e);
        int d = __builtin_nontemporal_load(idx + E_ + e);
        float4 hi = h[d], hj = h[s];
        float z[8], m1[8], z2[4];
        z1_of(hi, hj, w1, b1, z);
#pragma unroll
        for (int j = 0; j < 8; ++j) m1[j] = ftanh(z[j] * ss1[j] + ss1[8 + j]);
        mat8x4(m1, w2, b2, z2);
#pragma unroll
        for (int c = 0; c < 4; ++c) { a[c] += z2[c]; a[4 + c] += z2[c] * z2[c]; }
    }
    block_reduce_atomics<8>(a, sums2);
}

__global__ __launch_bounds__(256) void fb_scatter(const int* __restrict__ idx, const float4* __restrict__ h,
                                                  const float* __restrict__ w1, const float* __restrict__ b1,
                                                  const float* __restrict__ ss1,
                                                  const float* __restrict__ w2, const float* __restrict__ b2,
                                                  const float* __restrict__ ss2,
                                                  float* __restrict__ acc, int E_) {
    int stride = gridDim.x * blockDim.x;
    for (int e = blockIdx.x * blockDim.x + threadIdx.x; e < E_; e += stride) {
        int s = __builtin_nontemporal_load(idx + e);
        int d = __builtin_nontemporal_load(idx + E_ + e);
        float4 hi = h[d], hj = h[s];
        bool zero = (hi.x == hj.x) && (hi.y == hj.y) && (hi.z == hj.z) && (hi.w == hj.w);
        if (zero) continue;
        float z[8], m1[8], z2[4], m2[4];
        z1_of(hi, hj, w1, b1, z);
#pragma unroll
        for (int j = 0; j < 8; ++j) m1[j] = ftanh(z[j] * ss1[j] + ss1[8 + j]);
        mat8x4(m1, w2, b2, z2);
#pragma unroll
        for (int c = 0; c < 4; ++c) m2[c] = ftanh(z2[c] * ss2[c] + ss2[4 + c]);
        float* ap = acc + 8 * (size_t)d;
        atomicAdd(ap + 0, m2[0]);
        atomicAdd(ap + 1, m2[1]);
        atomicAdd(ap + 2, m2[2]);
        atomicAdd(ap + 3, m2[3]);
    }
}

// ---------------- node update MLP ----------------
__device__ __forceinline__ void load_u(int i, const float4* __restrict__ h,
                                       const float* __restrict__ acc, float* u) {
    float4 hv = h[i];
    const float* ap = acc + 8 * (size_t)i;
    float c = fmaxf(ap[4], 1.0f);
    u[0] = hv.x; u[1] = hv.y; u[2] = hv.z; u[3] = hv.w;
    u[4] = ap[0]; u[5] = ap[1]; u[6] = ap[2] / c; u[7] = ap[3] / c;
}

__global__ __launch_bounds__(256) void n_stats1(const float4* __restrict__ h,
                                                const float* __restrict__ acc,
                                                const float* __restrict__ w, const float* __restrict__ b,
                                                float* __restrict__ sums, int n) {
    float a[16];
#pragma unroll
    for (int i = 0; i < 16; ++i) a[i] = 0.f;
    int stride = gridDim.x * blockDim.x;
    for (int i = blockIdx.x * blockDim.x + threadIdx.x; i < n; i += stride) {
        float u[8], z[8];
        load_u(i, h, acc, u);
        mat8x8(u, w, b, z);
#pragma unroll
        for (int j = 0; j < 8; ++j) { a[j] += z[j]; a[8 + j] += z[j] * z[j]; }
    }
    block_reduce_atomics<16>(a, sums);
}

__global__ __launch_bounds__(256) void n_stats2(const float4* __restrict__ h,
                                                const float* __restrict__ acc,
                                                const float* __restrict__ w1, const float* __restrict__ b1,
                                                const float* __restrict__ ss3,
                                                const float* __restrict__ w2, const float* __restrict__ b2,
                                                float* __restrict__ sums, int n) {
    float a[8];
#pragma unroll
    for (int i = 0; i < 8; ++i) a[i] = 0.f;
    int stride = gridDim.x * blockDim.x;
    for (int i = blockIdx.x * blockDim.x + threadIdx.x; i < n; i += stride) {
        float u[8], z[8], u1[8], z4[4];
        load_u(i, h, acc, u);
        mat8x8(u, w1, b1, z);
#pragma unroll
        for (int j = 0; j < 8; ++j) u1[j] = ftanh(z[j] * ss3[j] + ss3[8 + j]);
        mat8x4(u1, w2, b2, z4);
#pragma unroll
        for (int c = 0; c < 4; ++c) { a[c] += z4[c]; a[4 + c] += z4[c] * z4[c]; }
    }
    block_reduce_atomics<8>(a, sums);
}

__global__ __launch_bounds__(256) void n_final(const float4* __restrict__ h,
                                               const float* __restrict__ acc,
                                               const float* __restrict__ w1, const float* __restrict__ b1,
                                               const float* __restrict__ ss3,
                                               const float* __restrict__ w2, const float* __restrict__ b2,
                                               const float* __restrict__ ss4,
                                               const float* __restrict__ pw, const float* __restrict__ pb,
                                               float2* __restrict__ out, int n) {
    int stride = gridDim.x * blockDim.x;
    for (int i = blockIdx.x * blockDim.x + threadIdx.x; i < n; i += stride) {
        float u[8], z[8], u1[8], z4[4], u2[4];
        load_u(i, h, acc, u);
        mat8x8(u, w1, b1, z);
#pragma unroll
        for (int j = 0; j < 8; ++j) u1[j] = ftanh(z[j] * ss3[j] + ss3[8 + j]);
        mat8x4(u1, w2, b2, z4);
#pragma unroll
        for (int c = 0; c < 4; ++c) u2[c] = ftanh(z4[c] * ss4[c] + ss4[4 + c]);
        float o0 = pb[0] + u2[0] * pw[0] + u2[1] * pw[2] + u2[2] * pw[4] + u2[3] * pw[6];
        float o1 = pb[1] + u2[0] * pw[1] + u2[1] * pw[3] + u2[2] * pw[5] + u2[3] * pw[7];
        out[i] = make_float2(o0, o1);
    }
}

extern "C" void kernel_launch(void* const* d_in, const int* in_sizes, int n_in,
                              void* d_out, int out_size, void* d_ws, size_t ws_size,
                              hipStream_t stream) {
    const float* pos  = (const float*)d_in[0];
    const float* vel  = (const float*)d_in[1];
    const int*   eidx = (const int*)d_in[2];
    const float* lin_w = (const float*)d_in[3];
    const float* lin_b = (const float*)d_in[4];
    const float* mw1 = (const float*)d_in[5];
    const float* mb1 = (const float*)d_in[6];
    const float* mg1 = (const float*)d_in[7];
    const float* mbe1 = (const float*)d_in[8];
    const float* mw2 = (const float*)d_in[9];
    const float* mb2 = (const float*)d_in[10];
    const float* mg2 = (const float*)d_in[11];
    const float* mbe2 = (const float*)d_in[12];
    const float* uw1 = (const float*)d_in[13];
    const float* ub1 = (const float*)d_in[14];
    const float* ug1 = (const float*)d_in[15];
    const float* ube1 = (const float*)d_in[16];
    const float* uw2 = (const float*)d_in[17];
    const float* ub2 = (const float*)d_in[18];
    const float* ug2 = (const float*)d_in[19];
    const float* ube2 = (const float*)d_in[20];
    const float* pw = (const float*)d_in[21];
    const float* pb = (const float*)d_in[22];

    int n  = in_sizes[0] / 2;
    int E_ = in_sizes[2] / 2;

    // ---- workspace layout (bump allocator, 16B aligned) ----
    char* base = (char*)d_ws;
    size_t off = 0;
    auto alloc = [&](size_t bytes) {
        off = (off + 15) & ~(size_t)15;
        void* p = base + off;
        off += bytes;
        return p;
    };
    float4*   h      = (float4*)alloc(16 * (size_t)n);         // 4 MB
    float*    acc    = (float*)alloc(32 * (size_t)n);          // 8 MB
    float*    sums   = (float*)alloc(512);                     // 64 stat sums + 64 scale/shift
    float*    ss     = sums + 64;
    uint32*   bbase  = (uint32*)alloc(4 * (NB + 1));
    uint32*   rowtot = (uint32*)alloc(4 * NB);
    uint32*   cntmat = (uint32*)alloc(4 * (size_t)NB * GB);    // 1 MB
    ushort16* ids    = (ushort16*)alloc(2 * (size_t)E_);       // 16 MB
    vf4*      rec    = (vf4*)alloc(16 * (size_t)E_);           // 128 MB
    size_t need_sort = off;                                     // ~157 MB

    bool big = ws_size >= need_sort;

    int nblk = (n + 255) / 256;
    int nbuckets = (n + 511) >> 9;
    int T = (E_ + GB - 1) / GB;

    k_h<<<nblk, 256, 0, stream>>>(pos, vel, lin_w, lin_b, h, n);

    if (big) {
        (void)hipMemsetAsync(sums, 0, 256, stream);   // zero the 64 accumulator floats

        k_cnt<<<GB, 256, 0, stream>>>(eidx + E_, cntmat, E_, T);
        k_scanA<<<NB, 256, 0, stream>>>(cntmat, rowtot);
        k_scanB<<<1, 256, 0, stream>>>(rowtot, bbase);

        k_reorder<<<GB, 256, 0, stream>>>(eidx, h, mw1, mb1, cntmat, bbase, rec, ids, sums, E_, T);
        k_fin<<<1, 64, 0, stream>>>(sums, ss, mg1, mbe1, 8, 1.0f / (float)E_);

        e_pass2<<<nbuckets, 256, 0, stream>>>(rec, ids, h, bbase, rowtot,
                                              mw1, mb1, ss, mw2, mb2, sums + 16, n);
        k_fin<<<1, 64, 0, stream>>>(sums + 16, ss + 16, mg2, mbe2, 4, 1.0f / (float)E_);

        e_aggr<<<nbuckets, 256, 0, stream>>>(rec, ids, h, bbase, rowtot,
                                             mw1, mb1, ss, mw2, mb2, ss + 16, acc, n);
    } else {
        (void)hipMemsetAsync(acc, 0, 32 * (size_t)n + 256, stream);

        fb_stats1<<<4096, 256, 0, stream>>>(eidx, h, mw1, mb1, sums, acc, E_);
        k_fin<<<1, 64, 0, stream>>>(sums, ss, mg1, mbe1, 8, 1.0f / (float)E_);

        fb_stats2<<<4096, 256, 0, stream>>>(eidx, h, mw1, mb1, ss, mw2, mb2, sums + 16, E_);
        k_fin<<<1, 64, 0, stream>>>(sums + 16, ss + 16, mg2, mbe2, 4, 1.0f / (float)E_);

        fb_scatter<<<4096, 256, 0, stream>>>(eidx, h, mw1, mb1, ss, mw2, mb2, ss + 16, acc, E_);
    }

    n_stats1<<<nblk, 256, 0, stream>>>(h, acc, uw1, ub1, sums + 24, n);
    k_fin<<<1, 64, 0, stream>>>(sums + 24, ss + 24, ug1, ube1, 8, 1.0f / (float)n);

    n_stats2<<<nblk, 256, 0, stream>>>(h, acc, uw1, ub1, ss + 24, uw2, ub2, sums + 40, n);
    k_fin<<<1, 64, 0, stream>>>(sums + 40, ss + 40, ug2, ube2, 4, 1.0f / (float)n);

    n_final<<<nblk, 256, 0, stream>>>(h, acc, uw1, ub1, ss + 24, uw2, ub2, ss + 40,
                                      pw, pb, (float2*)d_out, n);
}

// Round 9
// 620.435 us; speedup vs baseline: 3.4586x; 1.3617x over previous
//
#include <hip/hip_runtime.h>

#define EPSBN 1e-5f
#define NB 512            // buckets (dst >> 9), 512 nodes per bucket
#define GB 512            // blocks for cnt/reorder tiles

typedef float vf4 __attribute__((ext_vector_type(4)));
typedef int   vi2 __attribute__((ext_vector_type(2)));
typedef unsigned int uint32;

__device__ __forceinline__ float ftanh(float x) {
    return 1.0f - 2.0f / (__expf(2.0f * x) + 1.0f);
}

__device__ __forceinline__ float wave_sum(float v) {
#pragma unroll
    for (int off = 32; off > 0; off >>= 1) v += __shfl_down(v, off);
    return v;
}

__device__ __forceinline__ void z1_of(const float4 hi, const float4 hj,
                                      const float* __restrict__ w, const float* __restrict__ b,
                                      float* z) {
#pragma unroll
    for (int j = 0; j < 8; ++j) {
        z[j] = b[j]
             + hi.x * w[0 * 8 + j] + hi.y * w[1 * 8 + j] + hi.z * w[2 * 8 + j] + hi.w * w[3 * 8 + j]
             + hj.x * w[4 * 8 + j] + hj.y * w[5 * 8 + j] + hj.z * w[6 * 8 + j] + hj.w * w[7 * 8 + j];
    }
}

__device__ __forceinline__ void mat8x8(const float* u, const float* __restrict__ w,
                                       const float* __restrict__ b, float* z) {
#pragma unroll
    for (int j = 0; j < 8; ++j) {
        float t = b[j];
#pragma unroll
        for (int k = 0; k < 8; ++k) t += u[k] * w[k * 8 + j];
        z[j] = t;
    }
}

__device__ __forceinline__ void mat8x4(const float* u, const float* __restrict__ w,
                                       const float* __restrict__ b, float* z) {
#pragma unroll
    for (int c = 0; c < 4; ++c) {
        float t = b[c];
#pragma unroll
        for (int k = 0; k < 8; ++k) t += u[k] * w[k * 4 + c];
        z[c] = t;
    }
}

template <int NV>
__device__ __forceinline__ void block_reduce_atomics(float* a, float* __restrict__ sums) {
    __shared__ float red[NV * 4];
    int wid = threadIdx.x >> 6, lane = threadIdx.x & 63;
#pragma unroll
    for (int i = 0; i < NV; ++i) {
        float v = wave_sum(a[i]);
        if (lane == 0) red[i * 4 + wid] = v;
    }
    __syncthreads();
    if (threadIdx.x < NV) {
        float v = red[threadIdx.x * 4 + 0] + red[threadIdx.x * 4 + 1]
                + red[threadIdx.x * 4 + 2] + red[threadIdx.x * 4 + 3];
        atomicAdd(&sums[threadIdx.x], v);
    }
}

// ---------------- node input projection ----------------
__global__ __launch_bounds__(256) void k_h(const float* __restrict__ pos, const float* __restrict__ vel,
                                           const float* __restrict__ w, const float* __restrict__ b,
                                           float4* __restrict__ h, int n) {
    int i = blockIdx.x * blockDim.x + threadIdx.x;
    if (i >= n) return;
    float2 p = ((const float2*)pos)[i];
    float2 v = ((const float2*)vel)[i];
    float o[4];
#pragma unroll
    for (int d = 0; d < 4; ++d)
        o[d] = b[d] + p.x * w[0 * 4 + d] + p.y * w[1 * 4 + d] + v.x * w[2 * 4 + d] + v.y * w[3 * 4 + d];
    h[i] = make_float4(o[0], o[1], o[2], o[3]);
}

// ---------------- count: per-(block,bucket) histogram, LDS atomics only ----------------
__global__ __launch_bounds__(256) void k_cnt(const int* __restrict__ dst, uint32* __restrict__ cntmat,
                                             int E_, int T) {
    __shared__ uint32 hist[NB];
    for (int b = threadIdx.x; b < NB; b += 256) hist[b] = 0;
    __syncthreads();
    int lo = blockIdx.x * T, hi2 = min(E_, lo + T);
    for (int e = lo + threadIdx.x; e < hi2; e += 256) {
        int d = __builtin_nontemporal_load(dst + e);
        atomicAdd(&hist[d >> 9], 1u);
    }
    __syncthreads();
    for (int b = threadIdx.x; b < NB; b += 256)
        cntmat[(size_t)b * GB + blockIdx.x] = hist[b];
}

// block-scan of 512 uints (256 threads x 2), exclusive
__device__ __forceinline__ void scan512(uint32* v, uint32* excl_out, uint32* total) {
    __shared__ uint32 ts[256];
    uint32 local = v[0] + v[1];
    ts[threadIdx.x] = local;
    __syncthreads();
    for (int off = 1; off < 256; off <<= 1) {
        uint32 t = (threadIdx.x >= (uint32)off) ? ts[threadIdx.x - off] : 0u;
        __syncthreads();
        ts[threadIdx.x] += t;
        __syncthreads();
    }
    *excl_out = ts[threadIdx.x] - local;
    *total = ts[255];
}

__global__ __launch_bounds__(256) void k_scanA(uint32* __restrict__ cntmat, uint32* __restrict__ rowtot) {
    size_t base = (size_t)blockIdx.x * GB + threadIdx.x * 2;
    uint32 v[2];
    v[0] = cntmat[base]; v[1] = cntmat[base + 1];
    uint32 excl, tot;
    scan512(v, &excl, &tot);
    cntmat[base] = excl;
    cntmat[base + 1] = excl + v[0];
    if (threadIdx.x == 0) rowtot[blockIdx.x] = tot;
}

__global__ __launch_bounds__(256) void k_scanB(const uint32* __restrict__ rowtot, uint32* __restrict__ bbase) {
    uint32 v[2];
    v[0] = rowtot[threadIdx.x * 2]; v[1] = rowtot[threadIdx.x * 2 + 1];
    uint32 excl, tot;
    scan512(v, &excl, &tot);
    bbase[threadIdx.x * 2] = excl;
    bbase[threadIdx.x * 2 + 1] = excl + v[0];
    if (threadIdx.x == 0) bbase[NB] = tot;
}

// ---------------- reorder: pure 8B scatter (LDS cursors, no global atomics) ----------------
__global__ __launch_bounds__(256) void k_reorder(const int* __restrict__ idx,
                                                 const uint32* __restrict__ cntmat, const uint32* __restrict__ bbase,
                                                 vi2* __restrict__ sp, int E_, int T) {
    __shared__ uint32 cur[NB];
    for (int b = threadIdx.x; b < NB; b += 256)
        cur[b] = bbase[b] + cntmat[(size_t)b * GB + blockIdx.x];
    __syncthreads();
    int lo = blockIdx.x * T, hi2 = min(E_, lo + T);
    for (int e = lo + threadIdx.x; e < hi2; e += 256) {
        int s = __builtin_nontemporal_load(idx + e);
        int d = __builtin_nontemporal_load(idx + E_ + e);
        uint32 pos = atomicAdd(&cur[d >> 9], 1u);
        vi2 v = {s, d};
        sp[pos] = v;
    }
}

// ---------------- finalize BN stats -> scale/shift ----------------
__global__ void k_fin(const float* __restrict__ sums, float* __restrict__ ss,
                      const float* __restrict__ g, const float* __restrict__ be,
                      int d, float inv_count) {
    int j = threadIdx.x;
    if (j >= d) return;
    float mu = sums[j] * inv_count;
    float var = sums[d + j] * inv_count - mu * mu;
    float s = g[j] * rsqrtf(var + EPSBN);
    ss[j] = s;
    ss[d + j] = be[j] - mu * s;
}

// ---------------- E-stats1: grid-stride over sorted sp; h[dst] L1-local, h[src] L2 ----------------
__global__ __launch_bounds__(256) void e_stats1(const vi2* __restrict__ sp, const float4* __restrict__ h,
                                                const float* __restrict__ w1, const float* __restrict__ b1,
                                                float* __restrict__ sums, int E_) {
    float a[16];
#pragma unroll
    for (int i = 0; i < 16; ++i) a[i] = 0.f;
    int stride = gridDim.x * blockDim.x;
    for (int e = blockIdx.x * blockDim.x + threadIdx.x; e < E_; e += stride) {
        vi2 v = __builtin_nontemporal_load(&sp[e]);
        float4 hi = h[v.y], hj = h[v.x];
        float z[8];
        z1_of(hi, hj, w1, b1, z);
#pragma unroll
        for (int j = 0; j < 8; ++j) { a[j] += z[j]; a[8 + j] += z[j] * z[j]; }
    }
    block_reduce_atomics<16>(a, sums);
}

// ---------------- E2: grid-stride over sorted sp -> z2 stats ----------------
__global__ __launch_bounds__(256) void e_pass2(const vi2* __restrict__ sp, const float4* __restrict__ h,
                                               const float* __restrict__ w1, const float* __restrict__ b1,
                                               const float* __restrict__ ss1,
                                               const float* __restrict__ w2, const float* __restrict__ b2,
                                               float* __restrict__ sums2, int E_) {
    float a[8];
#pragma unroll
    for (int i = 0; i < 8; ++i) a[i] = 0.f;
    int stride = gridDim.x * blockDim.x;
    for (int e = blockIdx.x * blockDim.x + threadIdx.x; e < E_; e += stride) {
        vi2 v = __builtin_nontemporal_load(&sp[e]);
        float4 hi = h[v.y], hj = h[v.x];
        float z[8], m1[8], z2[4];
        z1_of(hi, hj, w1, b1, z);
#pragma unroll
        for (int j = 0; j < 8; ++j) m1[j] = ftanh(z[j] * ss1[j] + ss1[8 + j]);
        mat8x4(m1, w2, b2, z2);
#pragma unroll
        for (int c = 0; c < 4; ++c) { a[c] += z2[c]; a[4 + c] += z2[c] * z2[c]; }
    }
    block_reduce_atomics<8>(a, sums2);
}

// ---------------- aggregate: one block per bucket; LDS accumulators; no global atomics ----------------
__global__ __launch_bounds__(256) void e_aggr(const vi2* __restrict__ sp, const float4* __restrict__ h,
                                              const uint32* __restrict__ bbase, const uint32* __restrict__ rowtot,
                                              const float* __restrict__ w1, const float* __restrict__ b1,
                                              const float* __restrict__ ss1,
                                              const float* __restrict__ w2, const float* __restrict__ b2,
                                              const float* __restrict__ ss2,
                                              float* __restrict__ acc, int n) {
    __shared__ float lacc[512 * 5];
    int nodebase = blockIdx.x << 9;
    for (int k = threadIdx.x; k < 512 * 5; k += 256) lacc[k] = 0.f;
    __syncthreads();
    uint32 start = bbase[blockIdx.x];
    uint32 end = start + rowtot[blockIdx.x];
    for (uint32 e = start + threadIdx.x; e < end; e += 256) {
        vi2 v = __builtin_nontemporal_load(&sp[e]);
        int id = v.y - nodebase;
        float4 hi = h[v.y], hj = h[v.x];
        bool zero = (hi.x == hj.x) && (hi.y == hj.y) && (hi.z == hj.z) && (hi.w == hj.w);
        if (!zero) {
            float z[8], m1[8], z2[4], m2[4];
            z1_of(hi, hj, w1, b1, z);
#pragma unroll
            for (int j = 0; j < 8; ++j) m1[j] = ftanh(z[j] * ss1[j] + ss1[8 + j]);
            mat8x4(m1, w2, b2, z2);
#pragma unroll
            for (int c = 0; c < 4; ++c) m2[c] = ftanh(z2[c] * ss2[c] + ss2[4 + c]);
#pragma unroll
            for (int c = 0; c < 4; ++c) atomicAdd(&lacc[id * 5 + c], m2[c]);
        }
        atomicAdd(&lacc[id * 5 + 4], 1.0f);
    }
    __syncthreads();
    for (int k = threadIdx.x; k < 512; k += 256) {
        int node = nodebase + k;
        if (node < n) {
            float* ap = acc + 8 * (size_t)node;
            ap[0] = lacc[k * 5 + 0];
            ap[1] = lacc[k * 5 + 1];
            ap[2] = lacc[k * 5 + 2];
            ap[3] = lacc[k * 5 + 3];
            ap[4] = lacc[k * 5 + 4];
        }
    }
}

// ---------------- fallback edge kernels (round-1 style, used if ws too small) ----------------
__global__ __launch_bounds__(256) void fb_stats1(const int* __restrict__ idx, const float4* __restrict__ h,
                                                 const float* __restrict__ w1, const float* __restrict__ b1,
                                                 float* __restrict__ sums, float* __restrict__ acc, int E_) {
    float a[16];
#pragma unroll
    for (int i = 0; i < 16; ++i) a[i] = 0.f;
    int stride = gridDim.x * blockDim.x;
    for (int e = blockIdx.x * blockDim.x + threadIdx.x; e < E_; e += stride) {
        int s = __builtin_nontemporal_load(idx + e);
        int d = __builtin_nontemporal_load(idx + E_ + e);
        float4 hi = h[d], hj = h[s];
        float z[8];
        z1_of(hi, hj, w1, b1, z);
#pragma unroll
        for (int j = 0; j < 8; ++j) { a[j] += z[j]; a[8 + j] += z[j] * z[j]; }
        atomicAdd(acc + 8 * (size_t)d + 4, 1.0f);
    }
    block_reduce_atomics<16>(a, sums);
}

__global__ __launch_bounds__(256) void fb_stats2(const int* __restrict__ idx, const float4* __restrict__ h,
                                                 const float* __restrict__ w1, const float* __restrict__ b1,
                                                 const float* __restrict__ ss1,
                                                 const float* __restrict__ w2, const float* __restrict__ b2,
                                                 float* __restrict__ sums2, int E_) {
    float a[8];
#pragma unroll
    for (int i = 0; i < 8; ++i) a[i] = 0.f;
    int stride = gridDim.x * blockDim.x;
    for (int e = blockIdx.x * blockDim.x + threadIdx.x; e < E_; e += stride) {
        int s = __builtin_nontemporal_load(idx + e);
        int d = __builtin_nontemporal_load(idx + E_ + e);
        float4 hi = h[d], hj = h[s];
        float z[8], m1[8], z2[4];
        z1_of(hi, hj, w1, b1, z);
#pragma unroll
        for (int j = 0; j < 8; ++j) m1[j] = ftanh(z[j] * ss1[j] + ss1[8 + j]);
        mat8x4(m1, w2, b2, z2);
#pragma unroll
        for (int c = 0; c < 4; ++c) { a[c] += z2[c]; a[4 + c] += z2[c] * z2[c]; }
    }
    block_reduce_atomics<8>(a, sums2);
}

__global__ __launch_bounds__(256) void fb_scatter(const int* __restrict__ idx, const float4* __restrict__ h,
                                                  const float* __restrict__ w1, const float* __restrict__ b1,
                                                  const float* __restrict__ ss1,
                                                  const float* __restrict__ w2, const float* __restrict__ b2,
                                                  const float* __restrict__ ss2,
                                                  float* __restrict__ acc, int E_) {
    int stride = gridDim.x * blockDim.x;
    for (int e = blockIdx.x * blockDim.x + threadIdx.x; e < E_; e += stride) {
        int s = __builtin_nontemporal_load(idx + e);
        int d = __builtin_nontemporal_load(idx + E_ + e);
        float4 hi = h[d], hj = h[s];
        bool zero = (hi.x == hj.x) && (hi.y == hj.y) && (hi.z == hj.z) && (hi.w == hj.w);
        if (zero) continue;
        float z[8], m1[8], z2[4], m2[4];
        z1_of(hi, hj, w1, b1, z);
#pragma unroll
        for (int j = 0; j < 8; ++j) m1[j] = ftanh(z[j] * ss1[j] + ss1[8 + j]);
        mat8x4(m1, w2, b2, z2);
#pragma unroll
        for (int c = 0; c < 4; ++c) m2[c] = ftanh(z2[c] * ss2[c] + ss2[4 + c]);
        float* ap = acc + 8 * (size_t)d;
        atomicAdd(ap + 0, m2[0]);
        atomicAdd(ap + 1, m2[1]);
        atomicAdd(ap + 2, m2[2]);
        atomicAdd(ap + 3, m2[3]);
    }
}

// ---------------- node update MLP ----------------
__device__ __forceinline__ void load_u(int i, const float4* __restrict__ h,
                                       const float* __restrict__ acc, float* u) {
    float4 hv = h[i];
    const float* ap = acc + 8 * (size_t)i;
    float c = fmaxf(ap[4], 1.0f);
    u[0] = hv.x; u[1] = hv.y; u[2] = hv.z; u[3] = hv.w;
    u[4] = ap[0]; u[5] = ap[1]; u[6] = ap[2] / c; u[7] = ap[3] / c;
}

__global__ __launch_bounds__(256) void n_stats1(const float4* __restrict__ h,
                                                const float* __restrict__ acc,
                                                const float* __restrict__ w, const float* __restrict__ b,
                                                float* __restrict__ sums, int n) {
    float a[16];
#pragma unroll
    for (int i = 0; i < 16; ++i) a[i] = 0.f;
    int stride = gridDim.x * blockDim.x;
    for (int i = blockIdx.x * blockDim.x + threadIdx.x; i < n; i += stride) {
        float u[8], z[8];
        load_u(i, h, acc, u);
        mat8x8(u, w, b, z);
#pragma unroll
        for (int j = 0; j < 8; ++j) { a[j] += z[j]; a[8 + j] += z[j] * z[j]; }
    }
    block_reduce_atomics<16>(a, sums);
}

__global__ __launch_bounds__(256) void n_stats2(const float4* __restrict__ h,
                                                const float* __restrict__ acc,
                                                const float* __restrict__ w1, const float* __restrict__ b1,
                                                const float* __restrict__ ss3,
                                                const float* __restrict__ w2, const float* __restrict__ b2,
                                                float* __restrict__ sums, int n) {
    float a[8];
#pragma unroll
    for (int i = 0; i < 8; ++i) a[i] = 0.f;
    int stride = gridDim.x * blockDim.x;
    for (int i = blockIdx.x * blockDim.x + threadIdx.x; i < n; i += stride) {
        float u[8], z[8], u1[8], z4[4];
        load_u(i, h, acc, u);
        mat8x8(u, w1, b1, z);
#pragma unroll
        for (int j = 0; j < 8; ++j) u1[j] = ftanh(z[j] * ss3[j] + ss3[8 + j]);
        mat8x4(u1, w2, b2, z4);
#pragma unroll
        for (int c = 0; c < 4; ++c) { a[c] += z4[c]; a[4 + c] += z4[c] * z4[c]; }
    }
    block_reduce_atomics<8>(a, sums);
}

__global__ __launch_bounds__(256) void n_final(const float4* __restrict__ h,
                                               const float* __restrict__ acc,
                                               const float* __restrict__ w1, const float* __restrict__ b1,
                                               const float* __restrict__ ss3,
                                               const float* __restrict__ w2, const float* __restrict__ b2,
                                               const float* __restrict__ ss4,
                                               const float* __restrict__ pw, const float* __restrict__ pb,
                                               float2* __restrict__ out, int n) {
    int stride = gridDim.x * blockDim.x;
    for (int i = blockIdx.x * blockDim.x + threadIdx.x; i < n; i += stride) {
        float u[8], z[8], u1[8], z4[4], u2[4];
        load_u(i, h, acc, u);
        mat8x8(u, w1, b1, z);
#pragma unroll
        for (int j = 0; j < 8; ++j) u1[j] = ftanh(z[j] * ss3[j] + ss3[8 + j]);
        mat8x4(u1, w2, b2, z4);
#pragma unroll
        for (int c = 0; c < 4; ++c) u2[c] = ftanh(z4[c] * ss4[c] + ss4[4 + c]);
        float o0 = pb[0] + u2[0] * pw[0] + u2[1] * pw[2] + u2[2] * pw[4] + u2[3] * pw[6];
        float o1 = pb[1] + u2[0] * pw[1] + u2[1] * pw[3] + u2[2] * pw[5] + u2[3] * pw[7];
        out[i] = make_float2(o0, o1);
    }
}

extern "C" void kernel_launch(void* const* d_in, const int* in_sizes, int n_in,
                              void* d_out, int out_size, void* d_ws, size_t ws_size,
                              hipStream_t stream) {
    const float* pos  = (const float*)d_in[0];
    const float* vel  = (const float*)d_in[1];
    const int*   eidx = (const int*)d_in[2];
    const float* lin_w = (const float*)d_in[3];
    const float* lin_b = (const float*)d_in[4];
    const float* mw1 = (const float*)d_in[5];
    const float* mb1 = (const float*)d_in[6];
    const float* mg1 = (const float*)d_in[7];
    const float* mbe1 = (const float*)d_in[8];
    const float* mw2 = (const float*)d_in[9];
    const float* mb2 = (const float*)d_in[10];
    const float* mg2 = (const float*)d_in[11];
    const float* mbe2 = (const float*)d_in[12];
    const float* uw1 = (const float*)d_in[13];
    const float* ub1 = (const float*)d_in[14];
    const float* ug1 = (const float*)d_in[15];
    const float* ube1 = (const float*)d_in[16];
    const float* uw2 = (const float*)d_in[17];
    const float* ub2 = (const float*)d_in[18];
    const float* ug2 = (const float*)d_in[19];
    const float* ube2 = (const float*)d_in[20];
    const float* pw = (const float*)d_in[21];
    const float* pb = (const float*)d_in[22];

    int n  = in_sizes[0] / 2;
    int E_ = in_sizes[2] / 2;

    // ---- workspace layout (bump allocator, 16B aligned) ----
    char* base = (char*)d_ws;
    size_t off = 0;
    auto alloc = [&](size_t bytes) {
        off = (off + 15) & ~(size_t)15;
        void* p = base + off;
        off += bytes;
        return p;
    };
    float4* h      = (float4*)alloc(16 * (size_t)n);         // 4 MB
    float*  acc    = (float*)alloc(32 * (size_t)n);          // 8 MB
    float*  sums   = (float*)alloc(512);                     // 64 stat sums + 64 scale/shift
    float*  ss     = sums + 64;
    uint32* bbase  = (uint32*)alloc(4 * (NB + 1));
    uint32* rowtot = (uint32*)alloc(4 * NB);
    uint32* cntmat = (uint32*)alloc(4 * (size_t)NB * GB);    // 1 MB
    vi2*    sp     = (vi2*)alloc(8 * (size_t)E_);            // 64 MB
    size_t need_sort = off;                                   // ~78 MB

    bool big = ws_size >= need_sort;

    int nblk = (n + 255) / 256;
    int nbuckets = (n + 511) >> 9;
    int T = (E_ + GB - 1) / GB;

    k_h<<<nblk, 256, 0, stream>>>(pos, vel, lin_w, lin_b, h, n);

    if (big) {
        (void)hipMemsetAsync(sums, 0, 256, stream);   // zero the 64 accumulator floats

        k_cnt<<<GB, 256, 0, stream>>>(eidx + E_, cntmat, E_, T);
        k_scanA<<<NB, 256, 0, stream>>>(cntmat, rowtot);
        k_scanB<<<1, 256, 0, stream>>>(rowtot, bbase);

        k_reorder<<<GB, 256, 0, stream>>>(eidx, cntmat, bbase, sp, E_, T);

        e_stats1<<<2048, 256, 0, stream>>>(sp, h, mw1, mb1, sums, E_);
        k_fin<<<1, 64, 0, stream>>>(sums, ss, mg1, mbe1, 8, 1.0f / (float)E_);

        e_pass2<<<2048, 256, 0, stream>>>(sp, h, mw1, mb1, ss, mw2, mb2, sums + 16, E_);
        k_fin<<<1, 64, 0, stream>>>(sums + 16, ss + 16, mg2, mbe2, 4, 1.0f / (float)E_);

        e_aggr<<<nbuckets, 256, 0, stream>>>(sp, h, bbase, rowtot,
                                             mw1, mb1, ss, mw2, mb2, ss + 16, acc, n);
    } else {
        (void)hipMemsetAsync(acc, 0, 32 * (size_t)n + 256, stream);

        fb_stats1<<<4096, 256, 0, stream>>>(eidx, h, mw1, mb1, sums, acc, E_);
        k_fin<<<1, 64, 0, stream>>>(sums, ss, mg1, mbe1, 8, 1.0f / (float)E_);

        fb_stats2<<<4096, 256, 0, stream>>>(eidx, h, mw1, mb1, ss, mw2, mb2, sums + 16, E_);
        k_fin<<<1, 64, 0, stream>>>(sums + 16, ss + 16, mg2, mbe2, 4, 1.0f / (float)E_);

        fb_scatter<<<4096, 256, 0, stream>>>(eidx, h, mw1, mb1, ss, mw2, mb2, ss + 16, acc, E_);
    }

    n_stats1<<<nblk, 256, 0, stream>>>(h, acc, uw1, ub1, sums + 24, n);
    k_fin<<<1, 64, 0, stream>>>(sums + 24, ss + 24, ug1, ube1, 8, 1.0f / (float)n);

    n_stats2<<<nblk, 256, 0, stream>>>(h, acc, uw1, ub1, ss + 24, uw2, ub2, sums + 40, n);
    k_fin<<<1, 64, 0, stream>>>(sums + 40, ss + 40, ug2, ube2, 4, 1.0f / (float)n);

    n_final<<<nblk, 256, 0, stream>>>(h, acc, uw1, ub1, ss + 24, uw2, ub2, ss + 40,
                                      pw, pb, (float2*)d_out, n);
}